// Round 7
// baseline (1929.872 us; speedup 1.0000x reference)
//
#include <hip/hip_runtime.h>
#include <stdint.h>

typedef unsigned short u16;
typedef unsigned int u32;
typedef __attribute__((ext_vector_type(8))) short short8;
typedef __attribute__((ext_vector_type(8))) u16 u16x8;
typedef __attribute__((ext_vector_type(4))) float f32x4;
typedef __attribute__((ext_vector_type(2))) float f32x2;
typedef __attribute__((ext_vector_type(2))) u32 u32x2;

#define DEVINL static __device__ __forceinline__

#if !__has_builtin(__builtin_amdgcn_exp2f)
#define __builtin_amdgcn_exp2f(x) exp2f(x)
#endif
#if !__has_builtin(__builtin_amdgcn_rcpf)
#define __builtin_amdgcn_rcpf(x) (1.0f/(x))
#endif

#define MFMA16(a, b, c) __builtin_amdgcn_mfma_f32_16x16x32_bf16((a), (b), (c), 0, 0, 0)

constexpr float LOG2E_C    = 1.4426950408889634f;
constexpr float TWOLOG2E_C = 2.8853900817779268f;
constexpr float RSCALE_LG  = 1.4426950408889634f / 11.313708498984761f; // log2e / sqrt(128)

// ---------------- workspace layout (bytes) ----------------
constexpr size_t A256(size_t x){ return (x + 255) & ~(size_t)255; }
constexpr size_t OFS_EMB   = 0;                                         // u16 [8][2051][128] unmasked emb
constexpr size_t OFS_PAD   = A256(OFS_EMB  + (size_t)8*2051*128*2);     // u16 [8][2048][128] masked
constexpr size_t OFS_X1    = A256(OFS_PAD  + (size_t)8*2048*128*2);     // (unused now)
constexpr size_t OFS_X2    = A256(OFS_X1   + (size_t)8*2050*128*2);     // (unused now)
constexpr size_t OFS_QKVW  = A256(OFS_X2   + (size_t)8*2049*128*2);     // u16 [3][256][128] folded
constexpr size_t OFS_WA2   = A256(OFS_QKVW + (size_t)3*256*128*2);      // u16 [256][256]
constexpr size_t OFS_CONVW = A256(OFS_WA2  + (size_t)256*256*2);        // u16 [3][128][256]
constexpr size_t OFS_WIH0  = A256(OFS_CONVW+ (size_t)3*128*256*2);      // u16 [2][384][128]
constexpr size_t OFS_WIH1  = A256(OFS_WIH0 + (size_t)2*384*128*2);      // u16 [2][384][256]
constexpr size_t OFS_BIASX = A256(OFS_WIH1 + (size_t)2*384*256*2);      // f32 [2][2][384] scaled biases
constexpr size_t OFS_BHHN  = A256(OFS_BIASX+ (size_t)2*2*384*4);        // f32 [2][2][128] 2log2e*bhh_n
constexpr size_t OFS_Q     = A256(OFS_BHHN + (size_t)2*2*128*4);        // u16 [8][2048][256]
constexpr size_t OFS_K     = A256(OFS_Q    + (size_t)8*2048*256*2);
constexpr size_t OFS_V     = A256(OFS_K    + (size_t)8*2048*256*2);
constexpr size_t OFS_CS    = A256(OFS_V    + (size_t)8*2048*256*2);     // f32 [8][2048] colsum
constexpr size_t OFS_TM    = A256(OFS_CS   + (size_t)8*2048*4);         // f32 [8][128] tmean sums
constexpr size_t OFS_XG    = A256(OFS_TM   + (size_t)8*128*4);          // f32 [2][2048][8][384]
constexpr size_t OFS_H1    = A256(OFS_XG   + (size_t)2*2048*8*384*4);   // u16 [8][2048][256]
constexpr size_t OFS_ENC   = A256(OFS_H1   + (size_t)8*2048*256*2);     // u16 [8][2048][256]
constexpr size_t OFS_ENCW  = A256(OFS_ENC  + (size_t)8*2048*256*2);     // f32 [8][2048][256]
constexpr size_t OFS_SA    = A256(OFS_ENCW + (size_t)8*2048*256*4);     // f32 [8][256]
constexpr size_t OFS_RES   = A256(OFS_SA   + (size_t)8*256*4);          // f32 [8][2][2048]
constexpr size_t OFS_DV    = A256(OFS_RES  + (size_t)8*2*2048*4);       // f32 [8][2][256]

// ---------------- helpers ----------------
DEVINL u16 f2bf(float f){
  u32 u = __builtin_bit_cast(u32, f);
  u32 r = (u + 0x7FFFu + ((u >> 16) & 1u)) >> 16;
  return (u16)r;
}
DEVINL float bf2f(u16 s){ return __builtin_bit_cast(float, (u32)s << 16); }

DEVINL short8 ld8cvt(const float* p, float sc){
  short8 o;
#pragma unroll
  for (int e = 0; e < 8; ++e) o[e] = (short)f2bf(p[e]*sc);
  return o;
}

DEVINL u32 cvtpk(float lo, float hi){
  u32 r;
  asm("v_cvt_pk_bf16_f32 %0, %1, %2" : "=v"(r) : "v"(lo), "v"(hi));
  return r;
}

DEVINL float sel4(const f32x4 v, int rr){
  float a = (rr & 1) ? v[1] : v[0];
  float bq = (rr & 1) ? v[3] : v[2];
  return (rr & 2) ? bq : a;
}

// ---------------- prep: gathers, weight conversions, zeroing ----------------
__global__ __launch_bounds__(256) void k_prep(
    const int* tok, const int* lens, const float* embed,
    const float* wih0, const float* wih1,
    const float* bih0, const float* bhh0, const float* bih1, const float* bhh1,
    const float* convw, const float* WaW, const float* Qw, const float* Kw, const float* Vw,
    char* ws)
{
  u16* emb_bf   = (u16*)(ws + OFS_EMB);
  u16* pad_bf   = (u16*)(ws + OFS_PAD);
  u16* qkvw     = (u16*)(ws + OFS_QKVW);
  u16* wa2      = (u16*)(ws + OFS_WA2);
  u16* convw_bf = (u16*)(ws + OFS_CONVW);
  u16* wih0_bf  = (u16*)(ws + OFS_WIH0);
  u16* wih1_bf  = (u16*)(ws + OFS_WIH1);
  float* biasx  = (float*)(ws + OFS_BIASX);
  float* bhhn   = (float*)(ws + OFS_BHHN);
  float* colsum = (float*)(ws + OFS_CS);
  float* tmean  = (float*)(ws + OFS_TM);
  const int S0 = 8*2051*128, S1 = 8*2048*128, S2 = 3*256*128, S3 = 256*256, S4 = 3*128*256;
  const int S5 = 2*384*128, S6 = 2*384*256, S7 = 2*2*384 + 2*2*128, S8 = 8*2048 + 8*128;
  const int TOT = S0+S1+S2+S3+S4+S5+S6+S7+S8;
  for (int i = blockIdx.x*256 + threadIdx.x; i < TOT; i += gridDim.x*256){
    int j = i;
    if (j < S0){
      int b = j / (2051*128); int r = j - b*(2051*128); int t = r >> 7, dd = r & 127;
      emb_bf[j] = f2bf(embed[(size_t)tok[b*4000 + t]*128 + dd]);
      continue;
    }
    j -= S0;
    if (j < S1){
      int b = j >> 18; int r = j & 262143; int t = r >> 7, dd = r & 127;
      float v = (t < lens[b]) ? embed[(size_t)tok[b*4000 + t]*128 + dd] : 0.f;
      pad_bf[j] = f2bf(v); continue;
    }
    j -= S1;
    if (j < S2){
      int z = j >> 15; int r = j & 32767; int o = r >> 7, k2 = r & 127;
      const float* W = (z == 0) ? Qw : (z == 1) ? Kw : Vw;
      qkvw[j] = f2bf(W[o*256 + k2] + W[o*256 + 128 + k2]); continue;
    }
    j -= S2;
    if (j < S3){ int h = j >> 8, k2 = j & 255; wa2[j] = f2bf(WaW[(size_t)h*512 + 256 + k2]); continue; }
    j -= S3;
    if (j < S4){
      int ly = j >> 15; int r = j & 32767; int o = r >> 8, k2 = r & 255;
      int i2 = k2 & 127, kap = k2 >> 7;
      convw_bf[j] = f2bf(convw[((size_t)(ly*128 + o)*128 + i2)*2 + kap]); continue;
    }
    j -= S4;
    if (j < S5){ wih0_bf[j] = f2bf(wih0[j]); continue; }
    j -= S5;
    if (j < S6){ wih1_bf[j] = f2bf(wih1[j]); continue; }
    j -= S6;
    if (j < S7){
      if (j < 1536){
        int ly = j / 768; int r = j - ly*768; int d = r / 384, g = r % 384;
        float bi = (ly ? bih1 : bih0)[d*384 + g];
        float bh = (ly ? bhh1 : bhh0)[d*384 + g];
        biasx[j] = (g < 256) ? (-LOG2E_C*(bi + bh)) : (TWOLOG2E_C*bi);
      } else {
        int j2 = j - 1536; int ly = j2 >> 8; int r = j2 & 255; int d = r >> 7, jj = r & 127;
        bhhn[j2] = TWOLOG2E_C*((ly ? bhh1 : bhh0)[d*384 + 256 + jj]);
      }
      continue;
    }
    j -= S7;
    if (j < 8*2048) colsum[j] = 0.f; else tmean[j - 8*2048] = 0.f;
  }
}

// ---------------- xg = in @ Wih^T, scaled/biased for exp2-based gates ----------------
template<int KIN>
__global__ __launch_bounds__(256, 1) void k_xg(const int* lens, char* ws){
  const int tt = blockIdx.x, b = blockIdx.y, dir = blockIdx.z;
  constexpr int LAYER = (KIN == 128) ? 0 : 1;
  const u16* in = (KIN == 128) ? (const u16*)(ws + OFS_PAD) : (const u16*)(ws + OFS_H1);
  const u16* wmat = ((KIN == 128) ? (const u16*)(ws + OFS_WIH0) : (const u16*)(ws + OFS_WIH1))
                    + (size_t)dir*384*KIN;
  const float* biasx = (const float*)(ws + OFS_BIASX) + (LAYER*2 + dir)*384;
  float* xg = (float*)(ws + OFS_XG) + (size_t)dir*2048*3072;
  const int lenb = lens[b];
  __shared__ __align__(16) u16 sA[64][KIN + 8];
  constexpr int CH = KIN/8;
  const int tid = threadIdx.x, w = tid >> 6, l = tid & 63, rowg = l >> 4, cl = l & 15;
  for (int idx = tid; idx < 64*CH; idx += 256){
    int row = idx / CH, chn = idx % CH;
    int t = tt*64 + row;
    int tr = dir ? ((t < lenb) ? (lenb - 1 - t) : t) : t;
    *(u16x8*)&sA[row][chn*8] = *(const u16x8*)(in + ((size_t)(b*2048 + tr))*KIN + chn*8);
  }
  __syncthreads();
  f32x4 acc[24];
#pragma unroll
  for (int nt = 0; nt < 24; ++nt) acc[nt] = f32x4{0.f,0.f,0.f,0.f};
#pragma unroll
  for (int kk = 0; kk < KIN/32; ++kk){
    short8 a = *(const short8*)&sA[w*16 + cl][kk*32 + rowg*8];
#pragma unroll
    for (int nt = 0; nt < 24; ++nt){
      short8 bb = *(const short8*)(wmat + (size_t)(nt*16 + cl)*KIN + kk*32 + rowg*8);
      acc[nt] = MFMA16(a, bb, acc[nt]);
    }
  }
#pragma unroll
  for (int nt = 0; nt < 24; ++nt){
    const int g = nt*16 + cl;
    const float bx = biasx[g];
    const float sc = (nt < 16) ? -LOG2E_C : TWOLOG2E_C;
#pragma unroll
    for (int r = 0; r < 4; ++r){
      const int t = tt*64 + w*16 + rowg*4 + r;
      xg[((size_t)t*8 + b)*384 + g] = sc*acc[nt][r] + bx;
    }
  }
}

// ---------------- GRU recurrence block body ----------------
// One (dir,batch) per block, 8 waves, 256B broadcast h-tile in LDS.
// Each gate's K=128 accumulation is split into TWO independent depth-2 MFMA chains
// (k 0..63 with C=xg-init, k 64..127 with C=0, merged by sel4+add) -> 6 independent
// chains per wave / 12 per SIMD, hiding the dependent-MFMA latency that capped R4/R5.
// Prefetch indices are unclamped: reads for t>=2048 land in the allocated XG/H1
// workspace regions and the loaded values are never consumed.
DEVINL void rec_block(char* smem, const float* xg_all, const float* whh_all,
    const float* bhhn_all, const int* lens, u16* out, int dir, int b)
{
  const float* xg  = xg_all + (size_t)dir*2048*3072 + b*384;
  const float* whh = whh_all + (size_t)dir*384*128;
  const float* bnd = bhhn_all + dir*128;
  const int tid = threadIdx.x;
  const int u = tid >> 6, l = tid & 63;
  const int c = l & 15, q = l >> 4;
  const int rsel = c & 3;
  const int j = u*16 + q*4 + rsel;             // this lane's gate index within 128
  const bool writer = (c < 4);
  const bool dirb = (dir != 0);
  const int lenb = lens[b];

  u16 (*hbuf)[128] = (u16(*)[128])smem;        // [2][128]
  if (tid < 256) (&hbuf[0][0])[tid] = 0;

  short8 aR[4], aZ[4], aN[4];
#pragma unroll
  for (int kk = 0; kk < 4; ++kk){
    int k0 = kk*32 + q*8;
    int row = u*16 + c;
    aR[kk] = ld8cvt(whh + (size_t)(row)*128 + k0, -LOG2E_C);
    aZ[kk] = ld8cvt(whh + (size_t)(128 + row)*128 + k0, -LOG2E_C);
    aN[kk] = ld8cvt(whh + (size_t)(256 + row)*128 + k0, TWOLOG2E_C);
  }
  f32x4 bnU;
#pragma unroll
  for (int r = 0; r < 4; ++r) bnU[r] = bnd[u*16 + q*4 + r];
  const f32x4 z4 = {0.f, 0.f, 0.f, 0.f};

  const int offR = u*16 + q*4;          // float offset into xg[t] R section (Z at +128)
  const int offXN = 256 + j;            // this lane's XN scalar
  u16* outp = out + (size_t)b*2048*256 + dir*128 + j;
  float hp = 0.f;

#define LOAD_STAGE(T_, Rv, Zv, Xn) do {              \
    const float* pb_ = xg + (size_t)(T_)*3072;       \
    Rv = *(const f32x4*)(pb_ + offR);                \
    Zv = *(const f32x4*)(pb_ + offR + 128);          \
    Xn = pb_[offXN];                                 \
  } while (0)

#define REC_STEP(T_, PF_, CUR_, Rv, Zv, Xn) do {                                      \
    short8 bf0_ = *(const short8*)(&hbuf[CUR_][0] + (q*8 + 0*32));                    \
    short8 bf1_ = *(const short8*)(&hbuf[CUR_][0] + (q*8 + 1*32));                    \
    short8 bf2_ = *(const short8*)(&hbuf[CUR_][0] + (q*8 + 2*32));                    \
    short8 bf3_ = *(const short8*)(&hbuf[CUR_][0] + (q*8 + 3*32));                    \
    f32x4 cRa_ = MFMA16(aR[0], bf0_, Rv);                                             \
    f32x4 cZa_ = MFMA16(aZ[0], bf0_, Zv);                                             \
    f32x4 cNa_ = MFMA16(aN[0], bf0_, bnU);                                            \
    f32x4 cRb_ = MFMA16(aR[2], bf2_, z4);                                             \
    f32x4 cZb_ = MFMA16(aZ[2], bf2_, z4);                                             \
    f32x4 cNb_ = MFMA16(aN[2], bf2_, z4);                                             \
    const float* pfb_ = xg + (size_t)(PF_)*3072;                                      \
    Rv = *(const f32x4*)(pfb_ + offR);                                                \
    Zv = *(const f32x4*)(pfb_ + offR + 128);                                          \
    float Xnew_ = pfb_[offXN];                                                        \
    cRa_ = MFMA16(aR[1], bf1_, cRa_);                                                 \
    cZa_ = MFMA16(aZ[1], bf1_, cZa_);                                                 \
    cNa_ = MFMA16(aN[1], bf1_, cNa_);                                                 \
    cRb_ = MFMA16(aR[3], bf3_, cRb_);                                                 \
    cZb_ = MFMA16(aZ[3], bf3_, cZb_);                                                 \
    cNb_ = MFMA16(aN[3], bf3_, cNb_);                                                 \
    const bool v_ = (T_) < lenb;                                                      \
    float gR = sel4(cRa_, rsel) + sel4(cRb_, rsel);                                   \
    float gZ = sel4(cZa_, rsel) + sel4(cZb_, rsel);                                   \
    float gN = sel4(cNa_, rsel) + sel4(cNb_, rsel);                                   \
    float Rg = __builtin_amdgcn_rcpf(1.f + __builtin_amdgcn_exp2f(gR));               \
    float Zg = __builtin_amdgcn_rcpf(1.f + __builtin_amdgcn_exp2f(gZ));               \
    float y  = Xn + Rg*gN;                                                            \
    float NN = 1.f - 2.f*__builtin_amdgcn_rcpf(1.f + __builtin_amdgcn_exp2f(y));      \
    float hn = NN + Zg*(hp - NN);                                                     \
    hp = hn;                                                                          \
    Xn = Xnew_;                                                                       \
    u32 pk_ = cvtpk(hn, hn);                                                          \
    if (writer){                                                                      \
      hbuf[(CUR_) ^ 1][j] = (u16)pk_;                                                 \
      int to_ = dirb ? (v_ ? (lenb - 1 - (T_)) : (T_)) : (T_);                        \
      outp[(size_t)to_*256] = v_ ? (u16)pk_ : (u16)0;                                 \
    }                                                                                 \
    asm volatile("s_waitcnt lgkmcnt(0)" ::: "memory");                                \
    __builtin_amdgcn_s_barrier();                                                     \
  } while (0)

  f32x4 R0v, Z0v; float X0;
  f32x4 R1v, Z1v; float X1;
  f32x4 R2v, Z2v; float X2;
  f32x4 R3v, Z3v; float X3;
  __syncthreads();
  LOAD_STAGE(0, R0v, Z0v, X0);
  LOAD_STAGE(1, R1v, Z1v, X1);
  LOAD_STAGE(2, R2v, Z2v, X2);
  LOAD_STAGE(3, R3v, Z3v, X3);
  for (int t = 0; t < 2048; t += 4){
    REC_STEP(t + 0, t + 4, 0, R0v, Z0v, X0);
    REC_STEP(t + 1, t + 5, 1, R1v, Z1v, X1);
    REC_STEP(t + 2, t + 6, 0, R2v, Z2v, X2);
    REC_STEP(t + 3, t + 7, 1, R3v, Z3v, X3);
  }
#undef LOAD_STAGE
#undef REC_STEP
}

// ---------------- qkv role (256 active threads; barriers by all 512) ----------------
DEVINL void qkv_role(char* smem, char* ws, int tt, int b, int z){
  const u16* in = (const u16*)(ws + OFS_PAD);
  const u16* wmat = (const u16*)(ws + OFS_QKVW) + (size_t)z*256*128;
  u16* out = (u16*)(ws + ((z == 0) ? OFS_Q : (z == 1) ? OFS_K : OFS_V));
  u16 (*sA)[136] = (u16(*)[136])smem;
  const int tid = threadIdx.x;
  if (tid < 256){
    for (int idx = tid; idx < 64*16; idx += 256){
      int row = idx >> 4, chn = idx & 15;
      int t = tt*64 + row;
      *(u16x8*)&sA[row][chn*8] = *(const u16x8*)(in + ((size_t)(b*2048 + t))*128 + chn*8);
    }
  }
  __syncthreads();
  if (tid < 256){
    const int w = tid >> 6, l = tid & 63, rowg = l >> 4, cl = l & 15;
    f32x4 acc[16];
#pragma unroll
    for (int nt = 0; nt < 16; ++nt) acc[nt] = f32x4{0.f,0.f,0.f,0.f};
#pragma unroll
    for (int kk = 0; kk < 4; ++kk){
      short8 a = *(const short8*)&sA[w*16 + cl][kk*32 + rowg*8];
#pragma unroll
      for (int nt = 0; nt < 16; ++nt){
        short8 bb = *(const short8*)(wmat + (size_t)(nt*16 + cl)*128 + kk*32 + rowg*8);
        acc[nt] = MFMA16(a, bb, acc[nt]);
      }
    }
#pragma unroll
    for (int nt = 0; nt < 16; ++nt){
      int o = nt*16 + cl;
#pragma unroll
      for (int r = 0; r < 4; ++r){
        int t = tt*64 + w*16 + rowg*4 + r;
        out[((size_t)(b*2048 + t))*256 + o] = f2bf(acc[nt][r]);
      }
    }
  }
}

// ---------------- conv role: 3 layers fused in LDS with halo; writes only tmean ----------------
DEVINL void conv_layer_pass(u16 (*bi)[136], u16 (*bo)[136], const u16* wm, const float* bias,
                            int OUT_R, int w, int rowg, int cl){
#pragma unroll
  for (int pass = 0; pass < 2; ++pass){
    if (pass == 1 && !(w == 0 && OUT_R > 64)) break;
    const int rt = (pass == 0) ? w : 4;
    f32x4 acc[8];
#pragma unroll
    for (int nt = 0; nt < 8; ++nt) acc[nt] = f32x4{0.f,0.f,0.f,0.f};
#pragma unroll
    for (int kk = 0; kk < 8; ++kk){
      const int rofs = (kk >= 4) ? 1 : 0;
      short8 a = *(const short8*)&bi[rt*16 + cl + rofs][(kk & 3)*32 + rowg*8];
#pragma unroll
      for (int nt = 0; nt < 8; ++nt){
        short8 bb = *(const short8*)(wm + (size_t)(nt*16 + cl)*256 + kk*32 + rowg*8);
        acc[nt] = MFMA16(a, bb, acc[nt]);
      }
    }
#pragma unroll
    for (int nt = 0; nt < 8; ++nt){
      int o = nt*16 + cl;
      float bv = bias[o];
#pragma unroll
      for (int r = 0; r < 4; ++r){
        int ro = rt*16 + rowg*4 + r;
        if (ro < OUT_R) bo[ro][o] = f2bf(fmaxf(acc[nt][r] + bv, 0.f));
      }
    }
  }
}

DEVINL void conv_role(char* smem, const int* lens, const float* convb, char* ws, int tt, int b){
  const u16* emb = (const u16*)(ws + OFS_EMB);
  const u16* cw  = (const u16*)(ws + OFS_CONVW);
  float* tmean = (float*)(ws + OFS_TM);
  u16 (*bufA)[136] = (u16(*)[136])smem;                     // 82 rows
  u16 (*bufB)[136] = (u16(*)[136])(smem + 82*136*2);        // 82 rows
  const int tid = threadIdx.x;
  const int w = tid >> 6, l = tid & 63, rowg = l >> 4, cl = l & 15;
  if (tid < 256){
    for (int idx = tid; idx < 67*16; idx += 256){
      int row = idx >> 4, chn = idx & 15;
      *(u16x8*)&bufA[row][chn*8] = *(const u16x8*)(emb + ((size_t)(b*2051 + tt*64 + row))*128 + chn*8);
    }
  }
  __syncthreads();
  if (tid < 256) conv_layer_pass(bufA, bufB, cw + (size_t)0*128*256, convb + 0,   66, w, rowg, cl);
  __syncthreads();
  if (tid < 256) conv_layer_pass(bufB, bufA, cw + (size_t)1*128*256, convb + 128, 65, w, rowg, cl);
  __syncthreads();
  if (tid < 256){
    const int lenb = lens[b];
    const u16* wm = cw + (size_t)2*128*256;
    f32x4 acc[8];
#pragma unroll
    for (int nt = 0; nt < 8; ++nt) acc[nt] = f32x4{0.f,0.f,0.f,0.f};
#pragma unroll
    for (int kk = 0; kk < 8; ++kk){
      const int rofs = (kk >= 4) ? 1 : 0;
      short8 a = *(const short8*)&bufA[w*16 + cl + rofs][(kk & 3)*32 + rowg*8];
#pragma unroll
      for (int nt = 0; nt < 8; ++nt){
        short8 bb = *(const short8*)(wm + (size_t)(nt*16 + cl)*256 + kk*32 + rowg*8);
        acc[nt] = MFMA16(a, bb, acc[nt]);
      }
    }
#pragma unroll
    for (int nt = 0; nt < 8; ++nt){
      int o = nt*16 + cl;
      float bias = convb[2*128 + o];
      float s = 0.f;
#pragma unroll
      for (int r = 0; r < 4; ++r){
        int t = tt*64 + w*16 + rowg*4 + r;
        if (t < lenb) s += fmaxf(acc[nt][r] + bias, 0.f);
      }
      s += __shfl_xor(s, 16); s += __shfl_xor(s, 32);
      if (l < 16) atomicAdd(&tmean[b*128 + o], s);
    }
  }
}

// ---------------- scores role (256 active threads; barriers by all 512) ----------------
DEVINL void scores_role(char* smem, const int* lens, char* ws, int kt, int qt){
  const u16* Qp = (const u16*)(ws + OFS_Q);
  const u16* Kp = (const u16*)(ws + OFS_K);
  float* colsum = (float*)(ws + OFS_CS);
  u16 (*sQ)[264] = (u16(*)[264])smem;                       // 64x264
  u16 (*sK)[264] = (u16(*)[264])(smem + 64*264*2);
  float (*cbuf)[64] = (float(*)[64])(smem + 2*64*264*2);    // 8x64
  const int tid = threadIdx.x, w = tid >> 6, l = tid & 63, rowg = l >> 4, cl = l & 15;
  if (tid < 256)
    for (int i = tid; i < 512; i += 256) cbuf[i >> 6][i & 63] = 0.f;
  f32x4 c[8][4];
#pragma unroll
  for (int b = 0; b < 8; ++b)
#pragma unroll
    for (int nt = 0; nt < 4; ++nt) c[b][nt] = f32x4{0.f,0.f,0.f,0.f};
#pragma unroll
  for (int b = 0; b < 8; ++b){
    __syncthreads();
    if (tid < 256){
      for (int idx = tid; idx < 4096; idx += 256){
        int which = idx >> 11, row = (idx >> 5) & 63, ch = idx & 31;
        if (which){
          *(u16x8*)&sK[row][ch*8] = *(const u16x8*)(Kp + ((size_t)(b*2048 + kt*64 + row))*256 + ch*8);
        } else {
          *(u16x8*)&sQ[row][ch*8] = *(const u16x8*)(Qp + ((size_t)(b*2048 + qt*64 + row))*256 + ch*8);
        }
      }
    }
    __syncthreads();
    if (tid < 256){
#pragma unroll
      for (int kk = 0; kk < 8; ++kk){
        short8 a = *(const short8*)&sQ[w*16 + cl][kk*32 + rowg*8];
#pragma unroll
        for (int nt = 0; nt < 4; ++nt){
          short8 bb = *(const short8*)&sK[nt*16 + cl][kk*32 + rowg*8];
          c[b][nt] = MFMA16(a, bb, c[b][nt]);
        }
      }
    }
  }
  if (tid < 256){
    int lenv[8];
#pragma unroll
    for (int b = 0; b < 8; ++b) lenv[b] = lens[b];
    const int q0 = qt*64 + w*16 + rowg*4;
    float cs[8][4];
#pragma unroll
    for (int b = 0; b < 8; ++b)
#pragma unroll
      for (int nt = 0; nt < 4; ++nt) cs[b][nt] = 0.f;
#pragma unroll
    for (int nt = 0; nt < 4; ++nt){
#pragma unroll
      for (int r = 0; r < 4; ++r){
        float m = c[0][nt][r];
#pragma unroll
        for (int b = 1; b < 8; ++b) m = fmaxf(m, c[b][nt][r]);
        float e[8], s = 0.f;
#pragma unroll
        for (int b = 0; b < 8; ++b){ e[b] = __builtin_amdgcn_exp2f((c[b][nt][r] - m)*RSCALE_LG); s += e[b]; }
        float ri = __builtin_amdgcn_rcpf(s);
#pragma unroll
        for (int b = 0; b < 8; ++b)
          if (q0 + r < lenv[b]) cs[b][nt] += e[b]*ri;
      }
    }
#pragma unroll
    for (int b = 0; b < 8; ++b)
#pragma unroll
      for (int nt = 0; nt < 4; ++nt){
        float v = cs[b][nt];
        v += __shfl_xor(v, 16); v += __shfl_xor(v, 32);
        if (l < 16) atomicAdd(&cbuf[b][nt*16 + l], v);
      }
  }
  __syncthreads();
  if (tid < 256){
    for (int i = tid; i < 512; i += 256)
      atomicAdd(&colsum[(size_t)(i >> 6)*2048 + kt*64 + (i & 63)], cbuf[i >> 6][i & 63]);
  }
}

// ---------------- fused dispatch A: rec layer0 + qkv + conv ----------------
__global__ __launch_bounds__(512, 2) void k_fusedA(const int* lens, const float* convb, char* ws,
    const float* whh0, u16* outH1)
{
  __shared__ __align__(16) char smem[90112];   // 88KB -> 1 block/CU, protects rec CUs
  const int bid = blockIdx.x;
  if (bid < 16){
    rec_block(smem, (const float*)(ws + OFS_XG), whh0, (const float*)(ws + OFS_BHHN),
              lens, outH1, bid >> 3, bid & 7);
    return;
  }
  int r = bid - 16;
  if (r < 768){
    int z = r >> 8, rem = r & 255, b = rem >> 5, tt = rem & 31;
    qkv_role(smem, ws, tt, b, z);
    return;
  }
  r -= 768;  // [0,256): conv
  conv_role(smem, lens, convb, ws, r & 31, r >> 5);
}

// ---------------- fused dispatch B: rec layer1 + scores ----------------
__global__ __launch_bounds__(512, 2) void k_fusedB(const int* lens, char* ws,
    const float* whh1, u16* outENC)
{
  __shared__ __align__(16) char smem[90112];
  const int bid = blockIdx.x;
  if (bid < 16){
    rec_block(smem, (const float*)(ws + OFS_XG), whh1, (const float*)(ws + OFS_BHHN) + 2*128,
              lens, outENC, bid >> 3, bid & 7);
    return;
  }
  int r = bid - 16;           // [0,1024): scores
  scores_role(smem, lens, ws, r & 31, r >> 5);
}

// ---------------- tail1: encW tiles (bid<256) + sa role (bid>=256) ----------------
__global__ __launch_bounds__(256, 1) void k_tail1(char* ws){
  __shared__ __align__(16) u16 sA[64][264];
  const int bid = blockIdx.x;
  if (bid < 256){
    const int tt = bid & 31, b = bid >> 5;
    const u16* in = (const u16*)(ws + OFS_ENC);
    const u16* wmat = (const u16*)(ws + OFS_WA2);
    float* out = (float*)(ws + OFS_ENCW);
    const int tid = threadIdx.x, w = tid >> 6, l = tid & 63, rowg = l >> 4, cl = l & 15;
    for (int idx = tid; idx < 64*32; idx += 256){
      int row = idx >> 5, chn = idx & 31;
      int t = tt*64 + row;
      *(u16x8*)&sA[row][chn*8] = *(const u16x8*)(in + ((size_t)(b*2048 + t))*256 + chn*8);
    }
    __syncthreads();
    f32x4 acc[16];
#pragma unroll
    for (int nt = 0; nt < 16; ++nt) acc[nt] = f32x4{0.f,0.f,0.f,0.f};
#pragma unroll
    for (int kk = 0; kk < 8; ++kk){
      short8 a = *(const short8*)&sA[w*16 + cl][kk*32 + rowg*8];
#pragma unroll
      for (int nt = 0; nt < 16; ++nt){
        short8 bb = *(const short8*)(wmat + (size_t)(nt*16 + cl)*256 + kk*32 + rowg*8);
        acc[nt] = MFMA16(a, bb, acc[nt]);
      }
    }
#pragma unroll
    for (int nt = 0; nt < 16; ++nt){
      int h = nt*16 + cl;
#pragma unroll
      for (int r = 0; r < 4; ++r){
        int t = tt*64 + w*16 + rowg*4 + r;
        out[((size_t)(b*2048 + t))*256 + h] = acc[nt][r];
      }
    }
  } else {
    const int b = bid - 256, d = threadIdx.x;
    const float* cs = (const float*)(ws + OFS_CS) + (size_t)b*2048;
    const u16* V = (const u16*)(ws + OFS_V) + (size_t)b*2048*256;
    float a0 = 0.f, a1 = 0.f, a2 = 0.f, a3 = 0.f;
    for (int k = 0; k < 2048; k += 4){
      a0 += cs[k + 0]*bf2f(V[(size_t)(k + 0)*256 + d]);
      a1 += cs[k + 1]*bf2f(V[(size_t)(k + 1)*256 + d]);
      a2 += cs[k + 2]*bf2f(V[(size_t)(k + 2)*256 + d]);
      a3 += cs[k + 3]*bf2f(V[(size_t)(k + 3)*256 + d]);
    }
    ((float*)(ws + OFS_SA))[b*256 + d] = (a0 + a1) + (a2 + a3);
  }
}

// ---------------- additive-attn scores (pre-softmax, masked) ----------------
__global__ __launch_bounds__(256) void k_res(const int* lens, const float* WaW, const float* Wab,
    const float* VTw, const float* VTb, char* ws){
  const int b = blockIdx.x, x = blockIdx.y, chb = blockIdx.z;
  const float* tm = (const float*)(ws + OFS_TM) + b*128;
  const float* sa = (const float*)(ws + OFS_SA) + b*256;
  const float* encW = (const float*)(ws + OFS_ENCW);
  float* res = (float*)(ws + OFS_RES) + ((size_t)b*2 + x)*2048;
  __shared__ float sw[256];
  __shared__ float vt[256];
  const int tid = threadIdx.x;
  {
    int h = tid;
    float acc = Wab[h];
    if (x == 0){
      for (int j = 0; j < 128; ++j)
        acc += tm[j]*(1.f/2048.f)*(WaW[(size_t)h*512 + 2*j] + WaW[(size_t)h*512 + 2*j + 1]);
    } else {
      for (int k = 0; k < 256; ++k) acc += sa[k]*WaW[(size_t)h*512 + k];
    }
    sw[h] = acc;
    vt[h] = VTw[h];
  }
  __syncthreads();
  const int lenb = lens[b];
  const int lsub = tid >> 2, q = tid & 3;
  const float vtb = VTb[0];
#pragma unroll
  for (int pass = 0; pass < 4; ++pass){
    const int ll = chb*256 + pass*64 + lsub;
    const float* er = encW + ((size_t)(b*2048 + ll))*256 + q*64;
    float racc = 0.f;
    for (int j = 0; j < 64; ++j){
      float u = er[j] + sw[q*64 + j];
      float th = 1.f - 2.f*__builtin_amdgcn_rcpf(1.f + __builtin_amdgcn_exp2f(u*TWOLOG2E_C));
      racc += th*vt[q*64 + j];
    }
    racc += __shfl_xor(racc, 1);
    racc += __shfl_xor(racc, 2);
    if (q == 0) res[ll] = (ll < lenb) ? (racc + vtb) : 0.f;
  }
}

// ---------------- softmax over L + weighted enc sum → d1/d2 ----------------
__global__ __launch_bounds__(256) void k_attnfin(char* ws){
  const int b = blockIdx.x, x = blockIdx.y;
  const float* res = (const float*)(ws + OFS_RES) + ((size_t)b*2 + x)*2048;
  const u16* enc = (const u16*)(ws + OFS_ENC);
  float* dvec = (float*)(ws + OFS_DV);
  __shared__ float sv[2048];
  __shared__ float red[8];
  const int tid = threadIdx.x;
  float m = -3.0e38f;
  for (int i = tid; i < 2048; i += 256){ float v = res[i]; sv[i] = v; m = fmaxf(m, v); }
#pragma unroll
  for (int o = 1; o < 64; o <<= 1) m = fmaxf(m, __shfl_xor(m, o));
  if ((tid & 63) == 0) red[tid >> 6] = m;
  __syncthreads();
  m = fmaxf(fmaxf(red[0], red[1]), fmaxf(red[2], red[3]));
  __syncthreads();
  float s = 0.f;
  for (int i = tid; i < 2048; i += 256){ float e = __builtin_amdgcn_exp2f((sv[i] - m)*LOG2E_C); sv[i] = e; s += e; }
#pragma unroll
  for (int o = 1; o < 64; o <<= 1) s += __shfl_xor(s, o);
  if ((tid & 63) == 0) red[tid >> 6] = s;
  __syncthreads();
  const float S = red[0] + red[1] + red[2] + red[3];
  const float ri = 1.0f/S;
  const int h = tid;
  float a0 = 0.f, a1 = 0.f, a2 = 0.f, a3 = 0.f;
  for (int l0 = 0; l0 < 2048; l0 += 4){
    a0 += sv[l0 + 0]*bf2f(enc[((size_t)(b*2048 + l0 + 0))*256 + h]);
    a1 += sv[l0 + 1]*bf2f(enc[((size_t)(b*2048 + l0 + 1))*256 + h]);
    a2 += sv[l0 + 2]*bf2f(enc[((size_t)(b*2048 + l0 + 2))*256 + h]);
    a3 += sv[l0 + 3]*bf2f(enc[((size_t)(b*2048 + l0 + 3))*256 + h]);
  }
  dvec[((size_t)b*2 + x)*256 + h] = ((a0 + a1) + (a2 + a3))*ri;
}

// ---------------- final FC ----------------
__global__ __launch_bounds__(64) void k_final(const float* fcw, const float* fcb, char* ws, float* outp){
  const int i = threadIdx.x;
  if (i >= 48) return;
  const int b = i/6, o = i%6;
  const float* dv = (const float*)(ws + OFS_DV);
  float acc = fcb[o];
  for (int h = 0; h < 256; ++h)
    acc += 0.5f*(dv[((size_t)b*2 + 0)*256 + h] + dv[((size_t)b*2 + 1)*256 + h])*fcw[o*256 + h];
  outp[i] = acc;
}

// ---------------- host ----------------
extern "C" void kernel_launch(void* const* d_in, const int* in_sizes, int n_in,
                              void* d_out, int out_size, void* d_ws, size_t ws_size,
                              hipStream_t stream)
{
  const int* tok    = (const int*)d_in[0];
  const int* lens   = (const int*)d_in[1];
  const float* embed= (const float*)d_in[2];
  const float* wih0 = (const float*)d_in[3];
  const float* whh0 = (const float*)d_in[4];
  const float* bih0 = (const float*)d_in[5];
  const float* bhh0 = (const float*)d_in[6];
  const float* wih1 = (const float*)d_in[7];
  const float* whh1 = (const float*)d_in[8];
  const float* bih1 = (const float*)d_in[9];
  const float* bhh1 = (const float*)d_in[10];
  const float* convw= (const float*)d_in[11];
  const float* convb= (const float*)d_in[12];
  const float* WaW  = (const float*)d_in[13];
  const float* Wab  = (const float*)d_in[14];
  const float* VTw  = (const float*)d_in[15];
  const float* VTb  = (const float*)d_in[16];
  const float* Qw   = (const float*)d_in[17];
  const float* Kw   = (const float*)d_in[18];
  const float* Vw   = (const float*)d_in[19];
  const float* fcw  = (const float*)d_in[20];
  const float* fcb  = (const float*)d_in[21];
  char* ws = (char*)d_ws;
  float* outp = (float*)d_out;

  hipLaunchKernelGGL(k_prep, dim3(2048), dim3(256), 0, stream,
      tok, lens, embed, wih0, wih1, bih0, bhh0, bih1, bhh1, convw, WaW, Qw, Kw, Vw, ws);
  hipLaunchKernelGGL((k_xg<128>), dim3(32,8,2), dim3(256), 0, stream, lens, ws);
  hipLaunchKernelGGL(k_fusedA, dim3(16 + 768 + 256), dim3(512), 0, stream,
      lens, convb, ws, whh0, (u16*)(ws + OFS_H1));
  hipLaunchKernelGGL((k_xg<256>), dim3(32,8,2), dim3(256), 0, stream, lens, ws);
  hipLaunchKernelGGL(k_fusedB, dim3(16 + 1024), dim3(512), 0, stream,
      lens, ws, whh1, (u16*)(ws + OFS_ENC));
  hipLaunchKernelGGL(k_tail1, dim3(264), dim3(256), 0, stream, ws);
  hipLaunchKernelGGL(k_res, dim3(8,2,8), dim3(256), 0, stream, lens, WaW, Wab, VTw, VTb, ws);
  hipLaunchKernelGGL(k_attnfin, dim3(8,2), dim3(256), 0, stream, ws);
  hipLaunchKernelGGL(k_final, dim3(1), dim3(64), 0, stream, fcw, fcb, ws, outp);
  (void)in_sizes; (void)n_in; (void)out_size; (void)ws_size;
}

// Round 8
// 1738.874 us; speedup vs baseline: 1.1098x; 1.1098x over previous
//
#include <hip/hip_runtime.h>
#include <stdint.h>

typedef unsigned short u16;
typedef unsigned int u32;
typedef __attribute__((ext_vector_type(8))) short short8;
typedef __attribute__((ext_vector_type(8))) u16 u16x8;
typedef __attribute__((ext_vector_type(4))) float f32x4;
typedef __attribute__((ext_vector_type(2))) float f32x2;
typedef __attribute__((ext_vector_type(2))) u32 u32x2;

#define DEVINL static __device__ __forceinline__

#if !__has_builtin(__builtin_amdgcn_exp2f)
#define __builtin_amdgcn_exp2f(x) exp2f(x)
#endif
#if !__has_builtin(__builtin_amdgcn_rcpf)
#define __builtin_amdgcn_rcpf(x) (1.0f/(x))
#endif

#define MFMA16(a, b, c) __builtin_amdgcn_mfma_f32_16x16x32_bf16((a), (b), (c), 0, 0, 0)

constexpr float LOG2E_C    = 1.4426950408889634f;
constexpr float TWOLOG2E_C = 2.8853900817779268f;
constexpr float RSCALE_LG  = 1.4426950408889634f / 11.313708498984761f; // log2e / sqrt(128)

// ---------------- workspace layout (bytes) ----------------
constexpr size_t A256(size_t x){ return (x + 255) & ~(size_t)255; }
constexpr size_t OFS_EMB   = 0;                                         // u16 [8][2051][128] unmasked emb
constexpr size_t OFS_PAD   = A256(OFS_EMB  + (size_t)8*2051*128*2);     // u16 [8][2048][128] masked
constexpr size_t OFS_X1    = A256(OFS_PAD  + (size_t)8*2048*128*2);     // (unused now)
constexpr size_t OFS_X2    = A256(OFS_X1   + (size_t)8*2050*128*2);     // (unused now)
constexpr size_t OFS_QKVW  = A256(OFS_X2   + (size_t)8*2049*128*2);     // u16 [3][256][128] folded
constexpr size_t OFS_WA2   = A256(OFS_QKVW + (size_t)3*256*128*2);      // u16 [256][256]
constexpr size_t OFS_CONVW = A256(OFS_WA2  + (size_t)256*256*2);        // u16 [3][128][256]
constexpr size_t OFS_WIH0  = A256(OFS_CONVW+ (size_t)3*128*256*2);      // u16 [2][384][128]
constexpr size_t OFS_WIH1  = A256(OFS_WIH0 + (size_t)2*384*128*2);      // u16 [2][384][256]
constexpr size_t OFS_BIASX = A256(OFS_WIH1 + (size_t)2*384*256*2);      // f32 [2][2][384] scaled biases
constexpr size_t OFS_BHHN  = A256(OFS_BIASX+ (size_t)2*2*384*4);        // f32 [2][2][128] 2log2e*bhh_n
constexpr size_t OFS_Q     = A256(OFS_BHHN + (size_t)2*2*128*4);        // u16 [8][2048][256]
constexpr size_t OFS_K     = A256(OFS_Q    + (size_t)8*2048*256*2);
constexpr size_t OFS_V     = A256(OFS_K    + (size_t)8*2048*256*2);
constexpr size_t OFS_CS    = A256(OFS_V    + (size_t)8*2048*256*2);     // f32 [8][2048] colsum
constexpr size_t OFS_TM    = A256(OFS_CS   + (size_t)8*2048*4);         // f32 [8][128] tmean sums
constexpr size_t OFS_XG    = A256(OFS_TM   + (size_t)8*128*4);          // f32 [2][2048][8][384]
constexpr size_t OFS_H1    = A256(OFS_XG   + (size_t)2*2048*8*384*4);   // u16 [8][2048][256]
constexpr size_t OFS_ENC   = A256(OFS_H1   + (size_t)8*2048*256*2);     // u16 [8][2048][256]
constexpr size_t OFS_ENCW  = A256(OFS_ENC  + (size_t)8*2048*256*2);     // f32 [8][2048][256]
constexpr size_t OFS_SA    = A256(OFS_ENCW + (size_t)8*2048*256*4);     // f32 [8][256]
constexpr size_t OFS_RES   = A256(OFS_SA   + (size_t)8*256*4);          // f32 [8][2][2048]
constexpr size_t OFS_DV    = A256(OFS_RES  + (size_t)8*2*2048*4);       // f32 [8][2][256]

// ---------------- helpers ----------------
DEVINL u16 f2bf(float f){
  u32 u = __builtin_bit_cast(u32, f);
  u32 r = (u + 0x7FFFu + ((u >> 16) & 1u)) >> 16;
  return (u16)r;
}
DEVINL float bf2f(u16 s){ return __builtin_bit_cast(float, (u32)s << 16); }

DEVINL short8 ld8cvt(const float* p, float sc){
  short8 o;
#pragma unroll
  for (int e = 0; e < 8; ++e) o[e] = (short)f2bf(p[e]*sc);
  return o;
}

DEVINL u32 cvtpk(float lo, float hi){
  u32 r;
  asm("v_cvt_pk_bf16_f32 %0, %1, %2" : "=v"(r) : "v"(lo), "v"(hi));
  return r;
}

DEVINL float sel4(const f32x4 v, int rr){
  float a = (rr & 1) ? v[1] : v[0];
  float bq = (rr & 1) ? v[3] : v[2];
  return (rr & 2) ? bq : a;
}

// ---------------- prep: gathers, weight conversions, zeroing ----------------
__global__ __launch_bounds__(256) void k_prep(
    const int* tok, const int* lens, const float* embed,
    const float* wih0, const float* wih1,
    const float* bih0, const float* bhh0, const float* bih1, const float* bhh1,
    const float* convw, const float* WaW, const float* Qw, const float* Kw, const float* Vw,
    char* ws)
{
  u16* emb_bf   = (u16*)(ws + OFS_EMB);
  u16* pad_bf   = (u16*)(ws + OFS_PAD);
  u16* qkvw     = (u16*)(ws + OFS_QKVW);
  u16* wa2      = (u16*)(ws + OFS_WA2);
  u16* convw_bf = (u16*)(ws + OFS_CONVW);
  u16* wih0_bf  = (u16*)(ws + OFS_WIH0);
  u16* wih1_bf  = (u16*)(ws + OFS_WIH1);
  float* biasx  = (float*)(ws + OFS_BIASX);
  float* bhhn   = (float*)(ws + OFS_BHHN);
  float* colsum = (float*)(ws + OFS_CS);
  float* tmean  = (float*)(ws + OFS_TM);
  float* dvec   = (float*)(ws + OFS_DV);
  const int S0 = 8*2051*128, S1 = 8*2048*128, S2 = 3*256*128, S3 = 256*256, S4 = 3*128*256;
  const int S5 = 2*384*128, S6 = 2*384*256, S7 = 2*2*384 + 2*2*128;
  const int S8 = 8*2048 + 8*128 + 8*2*256;
  const int TOT = S0+S1+S2+S3+S4+S5+S6+S7+S8;
  for (int i = blockIdx.x*256 + threadIdx.x; i < TOT; i += gridDim.x*256){
    int j = i;
    if (j < S0){
      int b = j / (2051*128); int r = j - b*(2051*128); int t = r >> 7, dd = r & 127;
      emb_bf[j] = f2bf(embed[(size_t)tok[b*4000 + t]*128 + dd]);
      continue;
    }
    j -= S0;
    if (j < S1){
      int b = j >> 18; int r = j & 262143; int t = r >> 7, dd = r & 127;
      float v = (t < lens[b]) ? embed[(size_t)tok[b*4000 + t]*128 + dd] : 0.f;
      pad_bf[j] = f2bf(v); continue;
    }
    j -= S1;
    if (j < S2){
      int z = j >> 15; int r = j & 32767; int o = r >> 7, k2 = r & 127;
      const float* W = (z == 0) ? Qw : (z == 1) ? Kw : Vw;
      qkvw[j] = f2bf(W[o*256 + k2] + W[o*256 + 128 + k2]); continue;
    }
    j -= S2;
    if (j < S3){ int h = j >> 8, k2 = j & 255; wa2[j] = f2bf(WaW[(size_t)h*512 + 256 + k2]); continue; }
    j -= S3;
    if (j < S4){
      int ly = j >> 15; int r = j & 32767; int o = r >> 8, k2 = r & 255;
      int i2 = k2 & 127, kap = k2 >> 7;
      convw_bf[j] = f2bf(convw[((size_t)(ly*128 + o)*128 + i2)*2 + kap]); continue;
    }
    j -= S4;
    if (j < S5){ wih0_bf[j] = f2bf(wih0[j]); continue; }
    j -= S5;
    if (j < S6){ wih1_bf[j] = f2bf(wih1[j]); continue; }
    j -= S6;
    if (j < S7){
      if (j < 1536){
        int ly = j / 768; int r = j - ly*768; int d = r / 384, g = r % 384;
        float bi = (ly ? bih1 : bih0)[d*384 + g];
        float bh = (ly ? bhh1 : bhh0)[d*384 + g];
        biasx[j] = (g < 256) ? (-LOG2E_C*(bi + bh)) : (TWOLOG2E_C*bi);
      } else {
        int j2 = j - 1536; int ly = j2 >> 8; int r = j2 & 255; int d = r >> 7, jj = r & 127;
        bhhn[j2] = TWOLOG2E_C*((ly ? bhh1 : bhh0)[d*384 + 256 + jj]);
      }
      continue;
    }
    j -= S7;
    if (j < 8*2048){ colsum[j] = 0.f; continue; }
    j -= 8*2048;
    if (j < 8*128){ tmean[j] = 0.f; continue; }
    dvec[j - 8*128] = 0.f;
  }
}

// ---------------- xg = in @ Wih^T, scaled/biased for exp2-based gates ----------------
template<int KIN>
__global__ __launch_bounds__(256, 1) void k_xg(const int* lens, char* ws){
  const int tt = blockIdx.x, b = blockIdx.y, dir = blockIdx.z;
  constexpr int LAYER = (KIN == 128) ? 0 : 1;
  const u16* in = (KIN == 128) ? (const u16*)(ws + OFS_PAD) : (const u16*)(ws + OFS_H1);
  const u16* wmat = ((KIN == 128) ? (const u16*)(ws + OFS_WIH0) : (const u16*)(ws + OFS_WIH1))
                    + (size_t)dir*384*KIN;
  const float* biasx = (const float*)(ws + OFS_BIASX) + (LAYER*2 + dir)*384;
  float* xg = (float*)(ws + OFS_XG) + (size_t)dir*2048*3072;
  const int lenb = lens[b];
  __shared__ __align__(16) u16 sA[64][KIN + 8];
  constexpr int CH = KIN/8;
  const int tid = threadIdx.x, w = tid >> 6, l = tid & 63, rowg = l >> 4, cl = l & 15;
  for (int idx = tid; idx < 64*CH; idx += 256){
    int row = idx / CH, chn = idx % CH;
    int t = tt*64 + row;
    int tr = dir ? ((t < lenb) ? (lenb - 1 - t) : t) : t;
    *(u16x8*)&sA[row][chn*8] = *(const u16x8*)(in + ((size_t)(b*2048 + tr))*KIN + chn*8);
  }
  __syncthreads();
  f32x4 acc[24];
#pragma unroll
  for (int nt = 0; nt < 24; ++nt) acc[nt] = f32x4{0.f,0.f,0.f,0.f};
#pragma unroll
  for (int kk = 0; kk < KIN/32; ++kk){
    short8 a = *(const short8*)&sA[w*16 + cl][kk*32 + rowg*8];
#pragma unroll
    for (int nt = 0; nt < 24; ++nt){
      short8 bb = *(const short8*)(wmat + (size_t)(nt*16 + cl)*KIN + kk*32 + rowg*8);
      acc[nt] = MFMA16(a, bb, acc[nt]);
    }
  }
#pragma unroll
  for (int nt = 0; nt < 24; ++nt){
    const int g = nt*16 + cl;
    const float bx = biasx[g];
    const float sc = (nt < 16) ? -LOG2E_C : TWOLOG2E_C;
#pragma unroll
    for (int r = 0; r < 4; ++r){
      const int t = tt*64 + w*16 + rowg*4 + r;
      xg[((size_t)t*8 + b)*384 + g] = sc*acc[nt][r] + bx;
    }
  }
}

// ---------------- GRU recurrence block body (R4/R6-proven: depth-4 chains) ----------------
// One (dir,batch) per block, 8 waves, 256B broadcast h-tile in LDS.
// REVERTED from the R7 chain-split (it cost ~+100cy/step in extra VALU + regs).
// New in this round: s_setprio(1..0) around the MFMA cluster (T5) — with 2 waves/SIMD
// at staggered intra-step phases, the MFMA-entering wave preempts the sibling's issue.
DEVINL void rec_block(char* smem, const float* xg_all, const float* whh_all,
    const float* bhhn_all, const int* lens, u16* out, int dir, int b)
{
  const float* xg  = xg_all + (size_t)dir*2048*3072 + b*384;
  const float* whh = whh_all + (size_t)dir*384*128;
  const float* bnd = bhhn_all + dir*128;
  const int tid = threadIdx.x;
  const int u = tid >> 6, l = tid & 63;
  const int c = l & 15, q = l >> 4;
  const int rsel = c & 3;
  const int j = u*16 + q*4 + rsel;             // this lane's gate index within 128
  const bool writer = (c < 4);
  const bool dirb = (dir != 0);
  const int lenb = lens[b];

  u16 (*hbuf)[128] = (u16(*)[128])smem;        // [2][128]
  if (tid < 256) (&hbuf[0][0])[tid] = 0;

  short8 aR[4], aZ[4], aN[4];
#pragma unroll
  for (int kk = 0; kk < 4; ++kk){
    int k0 = kk*32 + q*8;
    int row = u*16 + c;
    aR[kk] = ld8cvt(whh + (size_t)(row)*128 + k0, -LOG2E_C);
    aZ[kk] = ld8cvt(whh + (size_t)(128 + row)*128 + k0, -LOG2E_C);
    aN[kk] = ld8cvt(whh + (size_t)(256 + row)*128 + k0, TWOLOG2E_C);
  }
  f32x4 bnU;
#pragma unroll
  for (int r = 0; r < 4; ++r) bnU[r] = bnd[u*16 + q*4 + r];

  const int offR = u*16 + q*4;          // float offset into xg[t] R section (Z at +128)
  const int offXN = 256 + j;            // this lane's XN scalar
  u16* outp = out + (size_t)b*2048*256 + dir*128 + j;
  float hp = 0.f;

#define LOAD_STAGE(T_, Rv, Zv, Xn) do {              \
    const float* pb_ = xg + (size_t)(T_)*3072;       \
    Rv = *(const f32x4*)(pb_ + offR);                \
    Zv = *(const f32x4*)(pb_ + offR + 128);          \
    Xn = pb_[offXN];                                 \
  } while (0)

#define REC_STEP(T_, PF_, CUR_, Rv, Zv, Xn) do {                                      \
    short8 bf0_ = *(const short8*)(&hbuf[CUR_][0] + (q*8 + 0*32));                    \
    short8 bf1_ = *(const short8*)(&hbuf[CUR_][0] + (q*8 + 1*32));                    \
    short8 bf2_ = *(const short8*)(&hbuf[CUR_][0] + (q*8 + 2*32));                    \
    short8 bf3_ = *(const short8*)(&hbuf[CUR_][0] + (q*8 + 3*32));                    \
    __builtin_amdgcn_s_setprio(1);                                                    \
    f32x4 cR_ = MFMA16(aR[0], bf0_, Rv);                                              \
    f32x4 cZ_ = MFMA16(aZ[0], bf0_, Zv);                                              \
    f32x4 cN_ = MFMA16(aN[0], bf0_, bnU);                                             \
    const float* pfb_ = xg + (size_t)(PF_)*3072;                                      \
    Rv = *(const f32x4*)(pfb_ + offR);                                                \
    Zv = *(const f32x4*)(pfb_ + offR + 128);                                          \
    float Xnew_ = pfb_[offXN];                                                        \
    cR_ = MFMA16(aR[1], bf1_, cR_);                                                   \
    cZ_ = MFMA16(aZ[1], bf1_, cZ_);                                                   \
    cN_ = MFMA16(aN[1], bf1_, cN_);                                                   \
    cR_ = MFMA16(aR[2], bf2_, cR_);                                                   \
    cZ_ = MFMA16(aZ[2], bf2_, cZ_);                                                   \
    cN_ = MFMA16(aN[2], bf2_, cN_);                                                   \
    cR_ = MFMA16(aR[3], bf3_, cR_);                                                   \
    cZ_ = MFMA16(aZ[3], bf3_, cZ_);                                                   \
    cN_ = MFMA16(aN[3], bf3_, cN_);                                                   \
    __builtin_amdgcn_s_setprio(0);                                                    \
    const bool v_ = (T_) < lenb;                                                      \
    float gR = sel4(cR_, rsel);                                                       \
    float gZ = sel4(cZ_, rsel);                                                       \
    float gN = sel4(cN_, rsel);                                                       \
    float Rg = __builtin_amdgcn_rcpf(1.f + __builtin_amdgcn_exp2f(gR));               \
    float Zg = __builtin_amdgcn_rcpf(1.f + __builtin_amdgcn_exp2f(gZ));               \
    float y  = Xn + Rg*gN;                                                            \
    float NN = 1.f - 2.f*__builtin_amdgcn_rcpf(1.f + __builtin_amdgcn_exp2f(y));      \
    float hn = NN + Zg*(hp - NN);                                                     \
    hp = hn;                                                                          \
    Xn = Xnew_;                                                                       \
    u32 pk_ = cvtpk(hn, hn);                                                          \
    if (writer){                                                                      \
      hbuf[(CUR_) ^ 1][j] = (u16)pk_;                                                 \
      int to_ = dirb ? (v_ ? (lenb - 1 - (T_)) : (T_)) : (T_);                        \
      outp[(size_t)to_*256] = v_ ? (u16)pk_ : (u16)0;                                 \
    }                                                                                 \
    asm volatile("s_waitcnt lgkmcnt(0)" ::: "memory");                                \
    __builtin_amdgcn_s_barrier();                                                     \
  } while (0)

  f32x4 R0v, Z0v; float X0;
  f32x4 R1v, Z1v; float X1;
  f32x4 R2v, Z2v; float X2;
  f32x4 R3v, Z3v; float X3;
  __syncthreads();
  LOAD_STAGE(0, R0v, Z0v, X0);
  LOAD_STAGE(1, R1v, Z1v, X1);
  LOAD_STAGE(2, R2v, Z2v, X2);
  LOAD_STAGE(3, R3v, Z3v, X3);
  for (int t = 0; t < 2048; t += 4){
    int p4 = (t + 4 < 2048) ? (t + 4) : 2047;
    int p5 = (t + 5 < 2048) ? (t + 5) : 2047;
    int p6 = (t + 6 < 2048) ? (t + 6) : 2047;
    int p7 = (t + 7 < 2048) ? (t + 7) : 2047;
    REC_STEP(t + 0, p4, 0, R0v, Z0v, X0);
    REC_STEP(t + 1, p5, 1, R1v, Z1v, X1);
    REC_STEP(t + 2, p6, 0, R2v, Z2v, X2);
    REC_STEP(t + 3, p7, 1, R3v, Z3v, X3);
  }
#undef LOAD_STAGE
#undef REC_STEP
}

// ---------------- qkv role (256 active threads; barriers by all 512) ----------------
DEVINL void qkv_role(char* smem, char* ws, int tt, int b, int z){
  const u16* in = (const u16*)(ws + OFS_PAD);
  const u16* wmat = (const u16*)(ws + OFS_QKVW) + (size_t)z*256*128;
  u16* out = (u16*)(ws + ((z == 0) ? OFS_Q : (z == 1) ? OFS_K : OFS_V));
  u16 (*sA)[136] = (u16(*)[136])smem;
  const int tid = threadIdx.x;
  if (tid < 256){
    for (int idx = tid; idx < 64*16; idx += 256){
      int row = idx >> 4, chn = idx & 15;
      int t = tt*64 + row;
      *(u16x8*)&sA[row][chn*8] = *(const u16x8*)(in + ((size_t)(b*2048 + t))*128 + chn*8);
    }
  }
  __syncthreads();
  if (tid < 256){
    const int w = tid >> 6, l = tid & 63, rowg = l >> 4, cl = l & 15;
    f32x4 acc[16];
#pragma unroll
    for (int nt = 0; nt < 16; ++nt) acc[nt] = f32x4{0.f,0.f,0.f,0.f};
#pragma unroll
    for (int kk = 0; kk < 4; ++kk){
      short8 a = *(const short8*)&sA[w*16 + cl][kk*32 + rowg*8];
#pragma unroll
      for (int nt = 0; nt < 16; ++nt){
        short8 bb = *(const short8*)(wmat + (size_t)(nt*16 + cl)*128 + kk*32 + rowg*8);
        acc[nt] = MFMA16(a, bb, acc[nt]);
      }
    }
#pragma unroll
    for (int nt = 0; nt < 16; ++nt){
      int o = nt*16 + cl;
#pragma unroll
      for (int r = 0; r < 4; ++r){
        int t = tt*64 + w*16 + rowg*4 + r;
        out[((size_t)(b*2048 + t))*256 + o] = f2bf(acc[nt][r]);
      }
    }
  }
}

// ---------------- conv role: 3 layers fused in LDS with halo; writes only tmean ----------------
DEVINL void conv_layer_pass(u16 (*bi)[136], u16 (*bo)[136], const u16* wm, const float* bias,
                            int OUT_R, int w, int rowg, int cl){
#pragma unroll
  for (int pass = 0; pass < 2; ++pass){
    if (pass == 1 && !(w == 0 && OUT_R > 64)) break;
    const int rt = (pass == 0) ? w : 4;
    f32x4 acc[8];
#pragma unroll
    for (int nt = 0; nt < 8; ++nt) acc[nt] = f32x4{0.f,0.f,0.f,0.f};
#pragma unroll
    for (int kk = 0; kk < 8; ++kk){
      const int rofs = (kk >= 4) ? 1 : 0;
      short8 a = *(const short8*)&bi[rt*16 + cl + rofs][(kk & 3)*32 + rowg*8];
#pragma unroll
      for (int nt = 0; nt < 8; ++nt){
        short8 bb = *(const short8*)(wm + (size_t)(nt*16 + cl)*256 + kk*32 + rowg*8);
        acc[nt] = MFMA16(a, bb, acc[nt]);
      }
    }
#pragma unroll
    for (int nt = 0; nt < 8; ++nt){
      int o = nt*16 + cl;
      float bv = bias[o];
#pragma unroll
      for (int r = 0; r < 4; ++r){
        int ro = rt*16 + rowg*4 + r;
        if (ro < OUT_R) bo[ro][o] = f2bf(fmaxf(acc[nt][r] + bv, 0.f));
      }
    }
  }
}

DEVINL void conv_role(char* smem, const int* lens, const float* convb, char* ws, int tt, int b){
  const u16* emb = (const u16*)(ws + OFS_EMB);
  const u16* cw  = (const u16*)(ws + OFS_CONVW);
  float* tmean = (float*)(ws + OFS_TM);
  u16 (*bufA)[136] = (u16(*)[136])smem;                     // 82 rows
  u16 (*bufB)[136] = (u16(*)[136])(smem + 82*136*2);        // 82 rows
  const int tid = threadIdx.x;
  const int w = tid >> 6, l = tid & 63, rowg = l >> 4, cl = l & 15;
  if (tid < 256){
    for (int idx = tid; idx < 67*16; idx += 256){
      int row = idx >> 4, chn = idx & 15;
      *(u16x8*)&bufA[row][chn*8] = *(const u16x8*)(emb + ((size_t)(b*2051 + tt*64 + row))*128 + chn*8);
    }
  }
  __syncthreads();
  if (tid < 256) conv_layer_pass(bufA, bufB, cw + (size_t)0*128*256, convb + 0,   66, w, rowg, cl);
  __syncthreads();
  if (tid < 256) conv_layer_pass(bufB, bufA, cw + (size_t)1*128*256, convb + 128, 65, w, rowg, cl);
  __syncthreads();
  if (tid < 256){
    const int lenb = lens[b];
    const u16* wm = cw + (size_t)2*128*256;
    f32x4 acc[8];
#pragma unroll
    for (int nt = 0; nt < 8; ++nt) acc[nt] = f32x4{0.f,0.f,0.f,0.f};
#pragma unroll
    for (int kk = 0; kk < 8; ++kk){
      const int rofs = (kk >= 4) ? 1 : 0;
      short8 a = *(const short8*)&bufA[w*16 + cl + rofs][(kk & 3)*32 + rowg*8];
#pragma unroll
      for (int nt = 0; nt < 8; ++nt){
        short8 bb = *(const short8*)(wm + (size_t)(nt*16 + cl)*256 + kk*32 + rowg*8);
        acc[nt] = MFMA16(a, bb, acc[nt]);
      }
    }
#pragma unroll
    for (int nt = 0; nt < 8; ++nt){
      int o = nt*16 + cl;
      float bias = convb[2*128 + o];
      float s = 0.f;
#pragma unroll
      for (int r = 0; r < 4; ++r){
        int t = tt*64 + w*16 + rowg*4 + r;
        if (t < lenb) s += fmaxf(acc[nt][r] + bias, 0.f);
      }
      s += __shfl_xor(s, 16); s += __shfl_xor(s, 32);
      if (l < 16) atomicAdd(&tmean[b*128 + o], s);
    }
  }
}

// ---------------- scores role (256 active threads; barriers by all 512) ----------------
DEVINL void scores_role(char* smem, const int* lens, char* ws, int kt, int qt){
  const u16* Qp = (const u16*)(ws + OFS_Q);
  const u16* Kp = (const u16*)(ws + OFS_K);
  float* colsum = (float*)(ws + OFS_CS);
  u16 (*sQ)[264] = (u16(*)[264])smem;                       // 64x264
  u16 (*sK)[264] = (u16(*)[264])(smem + 64*264*2);
  float (*cbuf)[64] = (float(*)[64])(smem + 2*64*264*2);    // 8x64
  const int tid = threadIdx.x, w = tid >> 6, l = tid & 63, rowg = l >> 4, cl = l & 15;
  if (tid < 256)
    for (int i = tid; i < 512; i += 256) cbuf[i >> 6][i & 63] = 0.f;
  f32x4 c[8][4];
#pragma unroll
  for (int b = 0; b < 8; ++b)
#pragma unroll
    for (int nt = 0; nt < 4; ++nt) c[b][nt] = f32x4{0.f,0.f,0.f,0.f};
#pragma unroll
  for (int b = 0; b < 8; ++b){
    __syncthreads();
    if (tid < 256){
      for (int idx = tid; idx < 4096; idx += 256){
        int which = idx >> 11, row = (idx >> 5) & 63, ch = idx & 31;
        if (which){
          *(u16x8*)&sK[row][ch*8] = *(const u16x8*)(Kp + ((size_t)(b*2048 + kt*64 + row))*256 + ch*8);
        } else {
          *(u16x8*)&sQ[row][ch*8] = *(const u16x8*)(Qp + ((size_t)(b*2048 + qt*64 + row))*256 + ch*8);
        }
      }
    }
    __syncthreads();
    if (tid < 256){
#pragma unroll
      for (int kk = 0; kk < 8; ++kk){
        short8 a = *(const short8*)&sQ[w*16 + cl][kk*32 + rowg*8];
#pragma unroll
        for (int nt = 0; nt < 4; ++nt){
          short8 bb = *(const short8*)&sK[nt*16 + cl][kk*32 + rowg*8];
          c[b][nt] = MFMA16(a, bb, c[b][nt]);
        }
      }
    }
  }
  if (tid < 256){
    int lenv[8];
#pragma unroll
    for (int b = 0; b < 8; ++b) lenv[b] = lens[b];
    const int q0 = qt*64 + w*16 + rowg*4;
    float cs[8][4];
#pragma unroll
    for (int b = 0; b < 8; ++b)
#pragma unroll
      for (int nt = 0; nt < 4; ++nt) cs[b][nt] = 0.f;
#pragma unroll
    for (int nt = 0; nt < 4; ++nt){
#pragma unroll
      for (int r = 0; r < 4; ++r){
        float m = c[0][nt][r];
#pragma unroll
        for (int b = 1; b < 8; ++b) m = fmaxf(m, c[b][nt][r]);
        float e[8], s = 0.f;
#pragma unroll
        for (int b = 0; b < 8; ++b){ e[b] = __builtin_amdgcn_exp2f((c[b][nt][r] - m)*RSCALE_LG); s += e[b]; }
        float ri = __builtin_amdgcn_rcpf(s);
#pragma unroll
        for (int b = 0; b < 8; ++b)
          if (q0 + r < lenv[b]) cs[b][nt] += e[b]*ri;
      }
    }
#pragma unroll
    for (int b = 0; b < 8; ++b)
#pragma unroll
      for (int nt = 0; nt < 4; ++nt){
        float v = cs[b][nt];
        v += __shfl_xor(v, 16); v += __shfl_xor(v, 32);
        if (l < 16) atomicAdd(&cbuf[b][nt*16 + l], v);
      }
  }
  __syncthreads();
  if (tid < 256){
    for (int i = tid; i < 512; i += 256)
      atomicAdd(&colsum[(size_t)(i >> 6)*2048 + kt*64 + (i & 63)], cbuf[i >> 6][i & 63]);
  }
}

// ---------------- fused dispatch A: rec layer0 + qkv + conv ----------------
__global__ __launch_bounds__(512, 2) void k_fusedA(const int* lens, const float* convb, char* ws,
    const float* whh0, u16* outH1)
{
  __shared__ __align__(16) char smem[90112];   // 88KB -> 1 block/CU, protects rec CUs
  const int bid = blockIdx.x;
  if (bid < 16){
    rec_block(smem, (const float*)(ws + OFS_XG), whh0, (const float*)(ws + OFS_BHHN),
              lens, outH1, bid >> 3, bid & 7);
    return;
  }
  int r = bid - 16;
  if (r < 768){
    int z = r >> 8, rem = r & 255, b = rem >> 5, tt = rem & 31;
    qkv_role(smem, ws, tt, b, z);
    return;
  }
  r -= 768;  // [0,256): conv
  conv_role(smem, lens, convb, ws, r & 31, r >> 5);
}

// ---------------- fused dispatch B: rec layer1 + scores ----------------
__global__ __launch_bounds__(512, 2) void k_fusedB(const int* lens, char* ws,
    const float* whh1, u16* outENC)
{
  __shared__ __align__(16) char smem[90112];
  const int bid = blockIdx.x;
  if (bid < 16){
    rec_block(smem, (const float*)(ws + OFS_XG), whh1, (const float*)(ws + OFS_BHHN) + 2*128,
              lens, outENC, bid >> 3, bid & 7);
    return;
  }
  int r = bid - 16;           // [0,1024): scores
  scores_role(smem, lens, ws, r & 31, r >> 5);
}

// ---------------- tail1: encW tiles (bid<256) + sa role (bid>=256) ----------------
__global__ __launch_bounds__(256, 1) void k_tail1(char* ws){
  __shared__ __align__(16) u16 sA[64][264];
  const int bid = blockIdx.x;
  if (bid < 256){
    const int tt = bid & 31, b = bid >> 5;
    const u16* in = (const u16*)(ws + OFS_ENC);
    const u16* wmat = (const u16*)(ws + OFS_WA2);
    float* out = (float*)(ws + OFS_ENCW);
    const int tid = threadIdx.x, w = tid >> 6, l = tid & 63, rowg = l >> 4, cl = l & 15;
    for (int idx = tid; idx < 64*32; idx += 256){
      int row = idx >> 5, chn = idx & 31;
      int t = tt*64 + row;
      *(u16x8*)&sA[row][chn*8] = *(const u16x8*)(in + ((size_t)(b*2048 + t))*256 + chn*8);
    }
    __syncthreads();
    f32x4 acc[16];
#pragma unroll
    for (int nt = 0; nt < 16; ++nt) acc[nt] = f32x4{0.f,0.f,0.f,0.f};
#pragma unroll
    for (int kk = 0; kk < 8; ++kk){
      short8 a = *(const short8*)&sA[w*16 + cl][kk*32 + rowg*8];
#pragma unroll
      for (int nt = 0; nt < 16; ++nt){
        short8 bb = *(const short8*)(wmat + (size_t)(nt*16 + cl)*256 + kk*32 + rowg*8);
        acc[nt] = MFMA16(a, bb, acc[nt]);
      }
    }
#pragma unroll
    for (int nt = 0; nt < 16; ++nt){
      int h = nt*16 + cl;
#pragma unroll
      for (int r = 0; r < 4; ++r){
        int t = tt*64 + w*16 + rowg*4 + r;
        out[((size_t)(b*2048 + t))*256 + h] = acc[nt][r];
      }
    }
  } else {
    const int b = bid - 256, d = threadIdx.x;
    const float* cs = (const float*)(ws + OFS_CS) + (size_t)b*2048;
    const u16* V = (const u16*)(ws + OFS_V) + (size_t)b*2048*256;
    float a0 = 0.f, a1 = 0.f, a2 = 0.f, a3 = 0.f;
    for (int k = 0; k < 2048; k += 4){
      a0 += cs[k + 0]*bf2f(V[(size_t)(k + 0)*256 + d]);
      a1 += cs[k + 1]*bf2f(V[(size_t)(k + 1)*256 + d]);
      a2 += cs[k + 2]*bf2f(V[(size_t)(k + 2)*256 + d]);
      a3 += cs[k + 3]*bf2f(V[(size_t)(k + 3)*256 + d]);
    }
    ((float*)(ws + OFS_SA))[b*256 + d] = (a0 + a1) + (a2 + a3);
  }
}

// ---------------- additive-attn scores (pre-softmax, masked) ----------------
__global__ __launch_bounds__(256) void k_res(const int* lens, const float* WaW, const float* Wab,
    const float* VTw, const float* VTb, char* ws){
  const int b = blockIdx.x, x = blockIdx.y, chb = blockIdx.z;
  const float* tm = (const float*)(ws + OFS_TM) + b*128;
  const float* sa = (const float*)(ws + OFS_SA) + b*256;
  const float* encW = (const float*)(ws + OFS_ENCW);
  float* res = (float*)(ws + OFS_RES) + ((size_t)b*2 + x)*2048;
  __shared__ float sw[256];
  __shared__ float vt[256];
  const int tid = threadIdx.x;
  {
    int h = tid;
    float acc = Wab[h];
    if (x == 0){
      for (int j = 0; j < 128; ++j)
        acc += tm[j]*(1.f/2048.f)*(WaW[(size_t)h*512 + 2*j] + WaW[(size_t)h*512 + 2*j + 1]);
    } else {
      for (int k = 0; k < 256; ++k) acc += sa[k]*WaW[(size_t)h*512 + k];
    }
    sw[h] = acc;
    vt[h] = VTw[h];
  }
  __syncthreads();
  const int lenb = lens[b];
  const int lsub = tid >> 2, q = tid & 3;
  const float vtb = VTb[0];
#pragma unroll
  for (int pass = 0; pass < 4; ++pass){
    const int ll = chb*256 + pass*64 + lsub;
    const float* er = encW + ((size_t)(b*2048 + ll))*256 + q*64;
    float racc = 0.f;
    for (int j = 0; j < 64; ++j){
      float u = er[j] + sw[q*64 + j];
      float th = 1.f - 2.f*__builtin_amdgcn_rcpf(1.f + __builtin_amdgcn_exp2f(u*TWOLOG2E_C));
      racc += th*vt[q*64 + j];
    }
    racc += __shfl_xor(racc, 1);
    racc += __shfl_xor(racc, 2);
    if (q == 0) res[ll] = (ll < lenb) ? (racc + vtb) : 0.f;
  }
}

// ---------------- softmax over L + weighted enc sum -> d1/d2 (4-way l-split) ----------------
// Each (b,x,ch) block redundantly computes the softmax stats from res (8KB read),
// then partial-sums a 512-row enc chunk and atomicAdds into dvec (zeroed in k_prep).
// Spreads the 1MB/block enc read across 4x the CUs (was per-CU-BW-bound at 16 blocks).
__global__ __launch_bounds__(256) void k_attnfin(char* ws){
  const int b = blockIdx.x, x = blockIdx.y, ch = blockIdx.z;
  const float* res = (const float*)(ws + OFS_RES) + ((size_t)b*2 + x)*2048;
  const u16* enc = (const u16*)(ws + OFS_ENC);
  float* dvec = (float*)(ws + OFS_DV);
  __shared__ float sv[2048];
  __shared__ float red[8];
  const int tid = threadIdx.x;
  float m = -3.0e38f;
  for (int i = tid; i < 2048; i += 256){ float v = res[i]; sv[i] = v; m = fmaxf(m, v); }
#pragma unroll
  for (int o = 1; o < 64; o <<= 1) m = fmaxf(m, __shfl_xor(m, o));
  if ((tid & 63) == 0) red[tid >> 6] = m;
  __syncthreads();
  m = fmaxf(fmaxf(red[0], red[1]), fmaxf(red[2], red[3]));
  __syncthreads();
  float s = 0.f;
  for (int i = tid; i < 2048; i += 256){ float e = __builtin_amdgcn_exp2f((sv[i] - m)*LOG2E_C); sv[i] = e; s += e; }
#pragma unroll
  for (int o = 1; o < 64; o <<= 1) s += __shfl_xor(s, o);
  if ((tid & 63) == 0) red[tid >> 6] = s;
  __syncthreads();
  const float S = red[0] + red[1] + red[2] + red[3];
  const float ri = 1.0f/S;
  const int h = tid;
  const int l0b = ch*512;
  float a0 = 0.f, a1 = 0.f, a2 = 0.f, a3 = 0.f;
  for (int l0 = l0b; l0 < l0b + 512; l0 += 4){
    a0 += sv[l0 + 0]*bf2f(enc[((size_t)(b*2048 + l0 + 0))*256 + h]);
    a1 += sv[l0 + 1]*bf2f(enc[((size_t)(b*2048 + l0 + 1))*256 + h]);
    a2 += sv[l0 + 2]*bf2f(enc[((size_t)(b*2048 + l0 + 2))*256 + h]);
    a3 += sv[l0 + 3]*bf2f(enc[((size_t)(b*2048 + l0 + 3))*256 + h]);
  }
  atomicAdd(&dvec[((size_t)b*2 + x)*256 + h], ((a0 + a1) + (a2 + a3))*ri);
}

// ---------------- final FC ----------------
__global__ __launch_bounds__(64) void k_final(const float* fcw, const float* fcb, char* ws, float* outp){
  const int i = threadIdx.x;
  if (i >= 48) return;
  const int b = i/6, o = i%6;
  const float* dv = (const float*)(ws + OFS_DV);
  float acc = fcb[o];
  for (int h = 0; h < 256; ++h)
    acc += 0.5f*(dv[((size_t)b*2 + 0)*256 + h] + dv[((size_t)b*2 + 1)*256 + h])*fcw[o*256 + h];
  outp[i] = acc;
}

// ---------------- host ----------------
extern "C" void kernel_launch(void* const* d_in, const int* in_sizes, int n_in,
                              void* d_out, int out_size, void* d_ws, size_t ws_size,
                              hipStream_t stream)
{
  const int* tok    = (const int*)d_in[0];
  const int* lens   = (const int*)d_in[1];
  const float* embed= (const float*)d_in[2];
  const float* wih0 = (const float*)d_in[3];
  const float* whh0 = (const float*)d_in[4];
  const float* bih0 = (const float*)d_in[5];
  const float* bhh0 = (const float*)d_in[6];
  const float* wih1 = (const float*)d_in[7];
  const float* whh1 = (const float*)d_in[8];
  const float* bih1 = (const float*)d_in[9];
  const float* bhh1 = (const float*)d_in[10];
  const float* convw= (const float*)d_in[11];
  const float* convb= (const float*)d_in[12];
  const float* WaW  = (const float*)d_in[13];
  const float* Wab  = (const float*)d_in[14];
  const float* VTw  = (const float*)d_in[15];
  const float* VTb  = (const float*)d_in[16];
  const float* Qw   = (const float*)d_in[17];
  const float* Kw   = (const float*)d_in[18];
  const float* Vw   = (const float*)d_in[19];
  const float* fcw  = (const float*)d_in[20];
  const float* fcb  = (const float*)d_in[21];
  char* ws = (char*)d_ws;
  float* outp = (float*)d_out;

  hipLaunchKernelGGL(k_prep, dim3(2048), dim3(256), 0, stream,
      tok, lens, embed, wih0, wih1, bih0, bhh0, bih1, bhh1, convw, WaW, Qw, Kw, Vw, ws);
  hipLaunchKernelGGL((k_xg<128>), dim3(32,8,2), dim3(256), 0, stream, lens, ws);
  hipLaunchKernelGGL(k_fusedA, dim3(16 + 768 + 256), dim3(512), 0, stream,
      lens, convb, ws, whh0, (u16*)(ws + OFS_H1));
  hipLaunchKernelGGL((k_xg<256>), dim3(32,8,2), dim3(256), 0, stream, lens, ws);
  hipLaunchKernelGGL(k_fusedB, dim3(16 + 1024), dim3(512), 0, stream,
      lens, ws, whh1, (u16*)(ws + OFS_ENC));
  hipLaunchKernelGGL(k_tail1, dim3(264), dim3(256), 0, stream, ws);
  hipLaunchKernelGGL(k_res, dim3(8,2,8), dim3(256), 0, stream, lens, WaW, Wab, VTw, VTb, ws);
  hipLaunchKernelGGL(k_attnfin, dim3(8,2,4), dim3(256), 0, stream, ws);
  hipLaunchKernelGGL(k_final, dim3(1), dim3(64), 0, stream, fcw, fcb, ws, outp);
  (void)in_sizes; (void)n_in; (void)out_size; (void)ws_size;
}

// Round 9
// 1707.939 us; speedup vs baseline: 1.1299x; 1.0181x over previous
//
#include <hip/hip_runtime.h>
#include <stdint.h>

typedef unsigned short u16;
typedef unsigned int u32;
typedef __attribute__((ext_vector_type(8))) short short8;
typedef __attribute__((ext_vector_type(8))) u16 u16x8;
typedef __attribute__((ext_vector_type(4))) float f32x4;
typedef __attribute__((ext_vector_type(2))) float f32x2;
typedef __attribute__((ext_vector_type(2))) u32 u32x2;

#define DEVINL static __device__ __forceinline__

#if !__has_builtin(__builtin_amdgcn_exp2f)
#define __builtin_amdgcn_exp2f(x) exp2f(x)
#endif
#if !__has_builtin(__builtin_amdgcn_rcpf)
#define __builtin_amdgcn_rcpf(x) (1.0f/(x))
#endif

#define MFMA16(a, b, c) __builtin_amdgcn_mfma_f32_16x16x32_bf16((a), (b), (c), 0, 0, 0)

constexpr float LOG2E_C    = 1.4426950408889634f;
constexpr float TWOLOG2E_C = 2.8853900817779268f;
constexpr float RSCALE_LG  = 1.4426950408889634f / 11.313708498984761f; // log2e / sqrt(128)

// ---------------- workspace layout (bytes) ----------------
constexpr size_t A256(size_t x){ return (x + 255) & ~(size_t)255; }
constexpr size_t OFS_EMB   = 0;                                         // u16 [8][2051][128] unmasked emb
constexpr size_t OFS_PAD   = A256(OFS_EMB  + (size_t)8*2051*128*2);     // u16 [8][2048][128] masked
constexpr size_t OFS_X1    = A256(OFS_PAD  + (size_t)8*2048*128*2);     // (unused now)
constexpr size_t OFS_X2    = A256(OFS_X1   + (size_t)8*2050*128*2);     // (unused now)
constexpr size_t OFS_QKVW  = A256(OFS_X2   + (size_t)8*2049*128*2);     // u16 [3][256][128] folded
constexpr size_t OFS_WA2   = A256(OFS_QKVW + (size_t)3*256*128*2);      // u16 [256][256]
constexpr size_t OFS_CONVW = A256(OFS_WA2  + (size_t)256*256*2);        // u16 [3][128][256]
constexpr size_t OFS_WIH0  = A256(OFS_CONVW+ (size_t)3*128*256*2);      // u16 [2][384][128]
constexpr size_t OFS_WIH1  = A256(OFS_WIH0 + (size_t)2*384*128*2);      // u16 [2][384][256]
constexpr size_t OFS_BIASX = A256(OFS_WIH1 + (size_t)2*384*256*2);      // f32 [2][2][384] scaled biases
constexpr size_t OFS_BHHN  = A256(OFS_BIASX+ (size_t)2*2*384*4);        // f32 [2][2][128] 2log2e*bhh_n
constexpr size_t OFS_Q     = A256(OFS_BHHN + (size_t)2*2*128*4);        // u16 [8][2048][256]
constexpr size_t OFS_K     = A256(OFS_Q    + (size_t)8*2048*256*2);
constexpr size_t OFS_V     = A256(OFS_K    + (size_t)8*2048*256*2);
constexpr size_t OFS_CS    = A256(OFS_V    + (size_t)8*2048*256*2);     // f32 [8][2048] colsum
constexpr size_t OFS_TM    = A256(OFS_CS   + (size_t)8*2048*4);         // f32 [8][128] tmean sums
constexpr size_t OFS_XG    = A256(OFS_TM   + (size_t)8*128*4);          // f32 [2][2048][8][384]
constexpr size_t OFS_H1    = A256(OFS_XG   + (size_t)2*2048*8*384*4);   // u16 [8][2048][256]
constexpr size_t OFS_ENC   = A256(OFS_H1   + (size_t)8*2048*256*2);     // u16 [8][2048][256]
constexpr size_t OFS_ENCW  = A256(OFS_ENC  + (size_t)8*2048*256*2);     // f32 (unused now)
constexpr size_t OFS_SA    = A256(OFS_ENCW + (size_t)8*2048*256*4);     // f32 [8][256]
constexpr size_t OFS_RES   = A256(OFS_SA   + (size_t)8*256*4);          // f32 [8][2][2048]
constexpr size_t OFS_DV    = A256(OFS_RES  + (size_t)8*2*2048*4);       // f32 [8][2][256]

// ---------------- helpers ----------------
DEVINL u16 f2bf(float f){
  u32 u = __builtin_bit_cast(u32, f);
  u32 r = (u + 0x7FFFu + ((u >> 16) & 1u)) >> 16;
  return (u16)r;
}
DEVINL float bf2f(u16 s){ return __builtin_bit_cast(float, (u32)s << 16); }

DEVINL short8 ld8cvt(const float* p, float sc){
  short8 o;
#pragma unroll
  for (int e = 0; e < 8; ++e) o[e] = (short)f2bf(p[e]*sc);
  return o;
}

DEVINL u32 cvtpk(float lo, float hi){
  u32 r;
  asm("v_cvt_pk_bf16_f32 %0, %1, %2" : "=v"(r) : "v"(lo), "v"(hi));
  return r;
}

DEVINL float sel4(const f32x4 v, int rr){
  float a = (rr & 1) ? v[1] : v[0];
  float bq = (rr & 1) ? v[3] : v[2];
  return (rr & 2) ? bq : a;
}

// ---------------- prep: vectorized gathers (8 elems/thread), weight conversions, zeroing ----------------
__global__ __launch_bounds__(256) void k_prep(
    const int* tok, const int* lens, const float* embed,
    const float* wih0, const float* wih1,
    const float* bih0, const float* bhh0, const float* bih1, const float* bhh1,
    const float* convw, const float* WaW, const float* Qw, const float* Kw, const float* Vw,
    char* ws)
{
  u16* emb_bf   = (u16*)(ws + OFS_EMB);
  u16* pad_bf   = (u16*)(ws + OFS_PAD);
  u16* qkvw     = (u16*)(ws + OFS_QKVW);
  u16* wa2      = (u16*)(ws + OFS_WA2);
  u16* convw_bf = (u16*)(ws + OFS_CONVW);
  u16* wih0_bf  = (u16*)(ws + OFS_WIH0);
  u16* wih1_bf  = (u16*)(ws + OFS_WIH1);
  float* biasx  = (float*)(ws + OFS_BIASX);
  float* bhhn   = (float*)(ws + OFS_BHHN);
  float* colsum = (float*)(ws + OFS_CS);
  float* tmean  = (float*)(ws + OFS_TM);
  float* dvec   = (float*)(ws + OFS_DV);
  float* sabuf  = (float*)(ws + OFS_SA);
  const int V0 = 8*2051*16;     // emb+pad, 8 elems per item
  const int V1 = 3*256*16;      // qkvw
  const int V2 = 256*32;        // wa2
  const int V3 = 3*128*32;      // convw
  const int V4 = 2*384*16;      // wih0
  const int V5 = 2*384*32;      // wih1
  const int V6 = 2*2*384 + 2*2*128;                 // biasx + bhhn (scalar)
  const int V7 = 8*2048 + 8*128 + 8*2*256 + 8*256;  // zeros: colsum, tmean, dvec, sa
  const int TOT = V0+V1+V2+V3+V4+V5+V6+V7;
  for (int i = blockIdx.x*256 + threadIdx.x; i < TOT; i += gridDim.x*256){
    int j = i;
    if (j < V0){
      int b = j / (2051*16); int r = j - b*(2051*16); int t = r >> 4, chn = r & 15;
      const float* ep = embed + (size_t)tok[b*4000 + t]*128 + chn*8;
      u16x8 pk;
#pragma unroll
      for (int e = 0; e < 8; ++e) pk[e] = f2bf(ep[e]);
      *(u16x8*)(emb_bf + ((size_t)(b*2051 + t))*128 + chn*8) = pk;
      if (t < 2048){
        u16x8 z = {0,0,0,0,0,0,0,0};
        *(u16x8*)(pad_bf + ((size_t)(b*2048 + t))*128 + chn*8) = (t < lens[b]) ? pk : z;
      }
      continue;
    }
    j -= V0;
    if (j < V1){
      int z = j / (256*16); int r = j - z*(256*16); int o = r >> 4, chn = r & 15;
      const float* W = (z == 0) ? Qw : (z == 1) ? Kw : Vw;
      const float* p0 = W + (size_t)o*256 + chn*8;
      u16x8 pk;
#pragma unroll
      for (int e = 0; e < 8; ++e) pk[e] = f2bf(p0[e] + p0[128 + e]);
      *(u16x8*)(qkvw + ((size_t)z*256 + o)*128 + chn*8) = pk;
      continue;
    }
    j -= V1;
    if (j < V2){
      int h = j >> 5, chn = j & 31;
      const float* p = WaW + (size_t)h*512 + 256 + chn*8;
      u16x8 pk;
#pragma unroll
      for (int e = 0; e < 8; ++e) pk[e] = f2bf(p[e]);
      *(u16x8*)(wa2 + (size_t)h*256 + chn*8) = pk;
      continue;
    }
    j -= V2;
    if (j < V3){
      int ly = j / (128*32); int r = j - ly*(128*32); int o = r >> 5, chn = r & 31;
      u16x8 pk;
#pragma unroll
      for (int e = 0; e < 8; ++e){
        int k2 = chn*8 + e; int i2 = k2 & 127, kap = k2 >> 7;
        pk[e] = f2bf(convw[((size_t)(ly*128 + o)*128 + i2)*2 + kap]);
      }
      *(u16x8*)(convw_bf + ((size_t)(ly*128 + o))*256 + chn*8) = pk;
      continue;
    }
    j -= V3;
    if (j < V4){
      const float* p = wih0 + (size_t)j*8;
      u16x8 pk;
#pragma unroll
      for (int e = 0; e < 8; ++e) pk[e] = f2bf(p[e]);
      *(u16x8*)(wih0_bf + (size_t)j*8) = pk;
      continue;
    }
    j -= V4;
    if (j < V5){
      const float* p = wih1 + (size_t)j*8;
      u16x8 pk;
#pragma unroll
      for (int e = 0; e < 8; ++e) pk[e] = f2bf(p[e]);
      *(u16x8*)(wih1_bf + (size_t)j*8) = pk;
      continue;
    }
    j -= V5;
    if (j < V6){
      if (j < 1536){
        int ly = j / 768; int r = j - ly*768; int d = r / 384, g = r % 384;
        float bi = (ly ? bih1 : bih0)[d*384 + g];
        float bh = (ly ? bhh1 : bhh0)[d*384 + g];
        biasx[j] = (g < 256) ? (-LOG2E_C*(bi + bh)) : (TWOLOG2E_C*bi);
      } else {
        int j2 = j - 1536; int ly = j2 >> 8; int r = j2 & 255; int d = r >> 7, jj = r & 127;
        bhhn[j2] = TWOLOG2E_C*((ly ? bhh1 : bhh0)[d*384 + 256 + jj]);
      }
      continue;
    }
    j -= V6;
    if (j < 8*2048){ colsum[j] = 0.f; continue; }
    j -= 8*2048;
    if (j < 8*128){ tmean[j] = 0.f; continue; }
    j -= 8*128;
    if (j < 8*2*256){ dvec[j] = 0.f; continue; }
    sabuf[j - 8*2*256] = 0.f;
  }
}

// ---------------- xg = in @ Wih^T, scaled/biased for exp2-based gates ----------------
template<int KIN>
__global__ __launch_bounds__(256, 1) void k_xg(const int* lens, char* ws){
  const int tt = blockIdx.x, b = blockIdx.y, dir = blockIdx.z;
  constexpr int LAYER = (KIN == 128) ? 0 : 1;
  const u16* in = (KIN == 128) ? (const u16*)(ws + OFS_PAD) : (const u16*)(ws + OFS_H1);
  const u16* wmat = ((KIN == 128) ? (const u16*)(ws + OFS_WIH0) : (const u16*)(ws + OFS_WIH1))
                    + (size_t)dir*384*KIN;
  const float* biasx = (const float*)(ws + OFS_BIASX) + (LAYER*2 + dir)*384;
  float* xg = (float*)(ws + OFS_XG) + (size_t)dir*2048*3072;
  const int lenb = lens[b];
  __shared__ __align__(16) u16 sA[64][KIN + 8];
  constexpr int CH = KIN/8;
  const int tid = threadIdx.x, w = tid >> 6, l = tid & 63, rowg = l >> 4, cl = l & 15;
  for (int idx = tid; idx < 64*CH; idx += 256){
    int row = idx / CH, chn = idx % CH;
    int t = tt*64 + row;
    int tr = dir ? ((t < lenb) ? (lenb - 1 - t) : t) : t;
    *(u16x8*)&sA[row][chn*8] = *(const u16x8*)(in + ((size_t)(b*2048 + tr))*KIN + chn*8);
  }
  __syncthreads();
  f32x4 acc[24];
#pragma unroll
  for (int nt = 0; nt < 24; ++nt) acc[nt] = f32x4{0.f,0.f,0.f,0.f};
#pragma unroll
  for (int kk = 0; kk < KIN/32; ++kk){
    short8 a = *(const short8*)&sA[w*16 + cl][kk*32 + rowg*8];
#pragma unroll
    for (int nt = 0; nt < 24; ++nt){
      short8 bb = *(const short8*)(wmat + (size_t)(nt*16 + cl)*KIN + kk*32 + rowg*8);
      acc[nt] = MFMA16(a, bb, acc[nt]);
    }
  }
#pragma unroll
  for (int nt = 0; nt < 24; ++nt){
    const int g = nt*16 + cl;
    const float bx = biasx[g];
    const float sc = (nt < 16) ? -LOG2E_C : TWOLOG2E_C;
#pragma unroll
    for (int r = 0; r < 4; ++r){
      const int t = tt*64 + w*16 + rowg*4 + r;
      xg[((size_t)t*8 + b)*384 + g] = sc*acc[nt][r] + bx;
    }
  }
}

// ---------------- GRU recurrence block body (R4/R6-proven: depth-4 chains) ----------------
DEVINL void rec_block(char* smem, const float* xg_all, const float* whh_all,
    const float* bhhn_all, const int* lens, u16* out, int dir, int b)
{
  const float* xg  = xg_all + (size_t)dir*2048*3072 + b*384;
  const float* whh = whh_all + (size_t)dir*384*128;
  const float* bnd = bhhn_all + dir*128;
  const int tid = threadIdx.x;
  const int u = tid >> 6, l = tid & 63;
  const int c = l & 15, q = l >> 4;
  const int rsel = c & 3;
  const int j = u*16 + q*4 + rsel;             // this lane's gate index within 128
  const bool writer = (c < 4);
  const bool dirb = (dir != 0);
  const int lenb = lens[b];

  u16 (*hbuf)[128] = (u16(*)[128])smem;        // [2][128]
  if (tid < 256) (&hbuf[0][0])[tid] = 0;

  short8 aR[4], aZ[4], aN[4];
#pragma unroll
  for (int kk = 0; kk < 4; ++kk){
    int k0 = kk*32 + q*8;
    int row = u*16 + c;
    aR[kk] = ld8cvt(whh + (size_t)(row)*128 + k0, -LOG2E_C);
    aZ[kk] = ld8cvt(whh + (size_t)(128 + row)*128 + k0, -LOG2E_C);
    aN[kk] = ld8cvt(whh + (size_t)(256 + row)*128 + k0, TWOLOG2E_C);
  }
  f32x4 bnU;
#pragma unroll
  for (int r = 0; r < 4; ++r) bnU[r] = bnd[u*16 + q*4 + r];

  const int offR = u*16 + q*4;          // float offset into xg[t] R section (Z at +128)
  const int offXN = 256 + j;            // this lane's XN scalar
  u16* outp = out + (size_t)b*2048*256 + dir*128 + j;
  float hp = 0.f;

#define LOAD_STAGE(T_, Rv, Zv, Xn) do {              \
    const float* pb_ = xg + (size_t)(T_)*3072;       \
    Rv = *(const f32x4*)(pb_ + offR);                \
    Zv = *(const f32x4*)(pb_ + offR + 128);          \
    Xn = pb_[offXN];                                 \
  } while (0)

#define REC_STEP(T_, PF_, CUR_, Rv, Zv, Xn) do {                                      \
    short8 bf0_ = *(const short8*)(&hbuf[CUR_][0] + (q*8 + 0*32));                    \
    short8 bf1_ = *(const short8*)(&hbuf[CUR_][0] + (q*8 + 1*32));                    \
    short8 bf2_ = *(const short8*)(&hbuf[CUR_][0] + (q*8 + 2*32));                    \
    short8 bf3_ = *(const short8*)(&hbuf[CUR_][0] + (q*8 + 3*32));                    \
    __builtin_amdgcn_s_setprio(1);                                                    \
    f32x4 cR_ = MFMA16(aR[0], bf0_, Rv);                                              \
    f32x4 cZ_ = MFMA16(aZ[0], bf0_, Zv);                                              \
    f32x4 cN_ = MFMA16(aN[0], bf0_, bnU);                                             \
    const float* pfb_ = xg + (size_t)(PF_)*3072;                                      \
    Rv = *(const f32x4*)(pfb_ + offR);                                                \
    Zv = *(const f32x4*)(pfb_ + offR + 128);                                          \
    float Xnew_ = pfb_[offXN];                                                        \
    cR_ = MFMA16(aR[1], bf1_, cR_);                                                   \
    cZ_ = MFMA16(aZ[1], bf1_, cZ_);                                                   \
    cN_ = MFMA16(aN[1], bf1_, cN_);                                                   \
    cR_ = MFMA16(aR[2], bf2_, cR_);                                                   \
    cZ_ = MFMA16(aZ[2], bf2_, cZ_);                                                   \
    cN_ = MFMA16(aN[2], bf2_, cN_);                                                   \
    cR_ = MFMA16(aR[3], bf3_, cR_);                                                   \
    cZ_ = MFMA16(aZ[3], bf3_, cZ_);                                                   \
    cN_ = MFMA16(aN[3], bf3_, cN_);                                                   \
    __builtin_amdgcn_s_setprio(0);                                                    \
    const bool v_ = (T_) < lenb;                                                      \
    float gR = sel4(cR_, rsel);                                                       \
    float gZ = sel4(cZ_, rsel);                                                       \
    float gN = sel4(cN_, rsel);                                                       \
    float Rg = __builtin_amdgcn_rcpf(1.f + __builtin_amdgcn_exp2f(gR));               \
    float Zg = __builtin_amdgcn_rcpf(1.f + __builtin_amdgcn_exp2f(gZ));               \
    float y  = Xn + Rg*gN;                                                            \
    float NN = 1.f - 2.f*__builtin_amdgcn_rcpf(1.f + __builtin_amdgcn_exp2f(y));      \
    float hn = NN + Zg*(hp - NN);                                                     \
    hp = hn;                                                                          \
    Xn = Xnew_;                                                                       \
    u32 pk_ = cvtpk(hn, hn);                                                          \
    if (writer){                                                                      \
      hbuf[(CUR_) ^ 1][j] = (u16)pk_;                                                 \
      int to_ = dirb ? (v_ ? (lenb - 1 - (T_)) : (T_)) : (T_);                        \
      outp[(size_t)to_*256] = v_ ? (u16)pk_ : (u16)0;                                 \
    }                                                                                 \
    asm volatile("s_waitcnt lgkmcnt(0)" ::: "memory");                                \
    __builtin_amdgcn_s_barrier();                                                     \
  } while (0)

  f32x4 R0v, Z0v; float X0;
  f32x4 R1v, Z1v; float X1;
  f32x4 R2v, Z2v; float X2;
  f32x4 R3v, Z3v; float X3;
  __syncthreads();
  LOAD_STAGE(0, R0v, Z0v, X0);
  LOAD_STAGE(1, R1v, Z1v, X1);
  LOAD_STAGE(2, R2v, Z2v, X2);
  LOAD_STAGE(3, R3v, Z3v, X3);
  for (int t = 0; t < 2048; t += 4){
    int p4 = (t + 4 < 2048) ? (t + 4) : 2047;
    int p5 = (t + 5 < 2048) ? (t + 5) : 2047;
    int p6 = (t + 6 < 2048) ? (t + 6) : 2047;
    int p7 = (t + 7 < 2048) ? (t + 7) : 2047;
    REC_STEP(t + 0, p4, 0, R0v, Z0v, X0);
    REC_STEP(t + 1, p5, 1, R1v, Z1v, X1);
    REC_STEP(t + 2, p6, 0, R2v, Z2v, X2);
    REC_STEP(t + 3, p7, 1, R3v, Z3v, X3);
  }
#undef LOAD_STAGE
#undef REC_STEP
}

// ---------------- qkv role (256 active threads; barriers by all 512) ----------------
DEVINL void qkv_role(char* smem, char* ws, int tt, int b, int z){
  const u16* in = (const u16*)(ws + OFS_PAD);
  const u16* wmat = (const u16*)(ws + OFS_QKVW) + (size_t)z*256*128;
  u16* out = (u16*)(ws + ((z == 0) ? OFS_Q : (z == 1) ? OFS_K : OFS_V));
  u16 (*sA)[136] = (u16(*)[136])smem;
  const int tid = threadIdx.x;
  if (tid < 256){
    for (int idx = tid; idx < 64*16; idx += 256){
      int row = idx >> 4, chn = idx & 15;
      int t = tt*64 + row;
      *(u16x8*)&sA[row][chn*8] = *(const u16x8*)(in + ((size_t)(b*2048 + t))*128 + chn*8);
    }
  }
  __syncthreads();
  if (tid < 256){
    const int w = tid >> 6, l = tid & 63, rowg = l >> 4, cl = l & 15;
    f32x4 acc[16];
#pragma unroll
    for (int nt = 0; nt < 16; ++nt) acc[nt] = f32x4{0.f,0.f,0.f,0.f};
#pragma unroll
    for (int kk = 0; kk < 4; ++kk){
      short8 a = *(const short8*)&sA[w*16 + cl][kk*32 + rowg*8];
#pragma unroll
      for (int nt = 0; nt < 16; ++nt){
        short8 bb = *(const short8*)(wmat + (size_t)(nt*16 + cl)*128 + kk*32 + rowg*8);
        acc[nt] = MFMA16(a, bb, acc[nt]);
      }
    }
#pragma unroll
    for (int nt = 0; nt < 16; ++nt){
      int o = nt*16 + cl;
#pragma unroll
      for (int r = 0; r < 4; ++r){
        int t = tt*64 + w*16 + rowg*4 + r;
        out[((size_t)(b*2048 + t))*256 + o] = f2bf(acc[nt][r]);
      }
    }
  }
}

// ---------------- conv role: 3 layers fused in LDS with halo; writes only tmean ----------------
DEVINL void conv_layer_pass(u16 (*bi)[136], u16 (*bo)[136], const u16* wm, const float* bias,
                            int OUT_R, int w, int rowg, int cl){
#pragma unroll
  for (int pass = 0; pass < 2; ++pass){
    if (pass == 1 && !(w == 0 && OUT_R > 64)) break;
    const int rt = (pass == 0) ? w : 4;
    f32x4 acc[8];
#pragma unroll
    for (int nt = 0; nt < 8; ++nt) acc[nt] = f32x4{0.f,0.f,0.f,0.f};
#pragma unroll
    for (int kk = 0; kk < 8; ++kk){
      const int rofs = (kk >= 4) ? 1 : 0;
      short8 a = *(const short8*)&bi[rt*16 + cl + rofs][(kk & 3)*32 + rowg*8];
#pragma unroll
      for (int nt = 0; nt < 8; ++nt){
        short8 bb = *(const short8*)(wm + (size_t)(nt*16 + cl)*256 + kk*32 + rowg*8);
        acc[nt] = MFMA16(a, bb, acc[nt]);
      }
    }
#pragma unroll
    for (int nt = 0; nt < 8; ++nt){
      int o = nt*16 + cl;
      float bv = bias[o];
#pragma unroll
      for (int r = 0; r < 4; ++r){
        int ro = rt*16 + rowg*4 + r;
        if (ro < OUT_R) bo[ro][o] = f2bf(fmaxf(acc[nt][r] + bv, 0.f));
      }
    }
  }
}

DEVINL void conv_role(char* smem, const int* lens, const float* convb, char* ws, int tt, int b){
  const u16* emb = (const u16*)(ws + OFS_EMB);
  const u16* cw  = (const u16*)(ws + OFS_CONVW);
  float* tmean = (float*)(ws + OFS_TM);
  u16 (*bufA)[136] = (u16(*)[136])smem;                     // 82 rows
  u16 (*bufB)[136] = (u16(*)[136])(smem + 82*136*2);        // 82 rows
  const int tid = threadIdx.x;
  const int w = tid >> 6, l = tid & 63, rowg = l >> 4, cl = l & 15;
  if (tid < 256){
    for (int idx = tid; idx < 67*16; idx += 256){
      int row = idx >> 4, chn = idx & 15;
      *(u16x8*)&bufA[row][chn*8] = *(const u16x8*)(emb + ((size_t)(b*2051 + tt*64 + row))*128 + chn*8);
    }
  }
  __syncthreads();
  if (tid < 256) conv_layer_pass(bufA, bufB, cw + (size_t)0*128*256, convb + 0,   66, w, rowg, cl);
  __syncthreads();
  if (tid < 256) conv_layer_pass(bufB, bufA, cw + (size_t)1*128*256, convb + 128, 65, w, rowg, cl);
  __syncthreads();
  if (tid < 256){
    const int lenb = lens[b];
    const u16* wm = cw + (size_t)2*128*256;
    f32x4 acc[8];
#pragma unroll
    for (int nt = 0; nt < 8; ++nt) acc[nt] = f32x4{0.f,0.f,0.f,0.f};
#pragma unroll
    for (int kk = 0; kk < 8; ++kk){
      const int rofs = (kk >= 4) ? 1 : 0;
      short8 a = *(const short8*)&bufA[w*16 + cl + rofs][(kk & 3)*32 + rowg*8];
#pragma unroll
      for (int nt = 0; nt < 8; ++nt){
        short8 bb = *(const short8*)(wm + (size_t)(nt*16 + cl)*256 + kk*32 + rowg*8);
        acc[nt] = MFMA16(a, bb, acc[nt]);
      }
    }
#pragma unroll
    for (int nt = 0; nt < 8; ++nt){
      int o = nt*16 + cl;
      float bias = convb[2*128 + o];
      float s = 0.f;
#pragma unroll
      for (int r = 0; r < 4; ++r){
        int t = tt*64 + w*16 + rowg*4 + r;
        if (t < lenb) s += fmaxf(acc[nt][r] + bias, 0.f);
      }
      s += __shfl_xor(s, 16); s += __shfl_xor(s, 32);
      if (l < 16) atomicAdd(&tmean[b*128 + o], s);
    }
  }
}

// ---------------- scores role (256 active threads; barriers by all 512) ----------------
DEVINL void scores_role(char* smem, const int* lens, char* ws, int kt, int qt){
  const u16* Qp = (const u16*)(ws + OFS_Q);
  const u16* Kp = (const u16*)(ws + OFS_K);
  float* colsum = (float*)(ws + OFS_CS);
  u16 (*sQ)[264] = (u16(*)[264])smem;                       // 64x264
  u16 (*sK)[264] = (u16(*)[264])(smem + 64*264*2);
  float (*cbuf)[64] = (float(*)[64])(smem + 2*64*264*2);    // 8x64
  const int tid = threadIdx.x, w = tid >> 6, l = tid & 63, rowg = l >> 4, cl = l & 15;
  if (tid < 256)
    for (int i = tid; i < 512; i += 256) cbuf[i >> 6][i & 63] = 0.f;
  f32x4 c[8][4];
#pragma unroll
  for (int b = 0; b < 8; ++b)
#pragma unroll
    for (int nt = 0; nt < 4; ++nt) c[b][nt] = f32x4{0.f,0.f,0.f,0.f};
#pragma unroll
  for (int b = 0; b < 8; ++b){
    __syncthreads();
    if (tid < 256){
      for (int idx = tid; idx < 4096; idx += 256){
        int which = idx >> 11, row = (idx >> 5) & 63, ch = idx & 31;
        if (which){
          *(u16x8*)&sK[row][ch*8] = *(const u16x8*)(Kp + ((size_t)(b*2048 + kt*64 + row))*256 + ch*8);
        } else {
          *(u16x8*)&sQ[row][ch*8] = *(const u16x8*)(Qp + ((size_t)(b*2048 + qt*64 + row))*256 + ch*8);
        }
      }
    }
    __syncthreads();
    if (tid < 256){
#pragma unroll
      for (int kk = 0; kk < 8; ++kk){
        short8 a = *(const short8*)&sQ[w*16 + cl][kk*32 + rowg*8];
#pragma unroll
        for (int nt = 0; nt < 4; ++nt){
          short8 bb = *(const short8*)&sK[nt*16 + cl][kk*32 + rowg*8];
          c[b][nt] = MFMA16(a, bb, c[b][nt]);
        }
      }
    }
  }
  if (tid < 256){
    int lenv[8];
#pragma unroll
    for (int b = 0; b < 8; ++b) lenv[b] = lens[b];
    const int q0 = qt*64 + w*16 + rowg*4;
    float cs[8][4];
#pragma unroll
    for (int b = 0; b < 8; ++b)
#pragma unroll
      for (int nt = 0; nt < 4; ++nt) cs[b][nt] = 0.f;
#pragma unroll
    for (int nt = 0; nt < 4; ++nt){
#pragma unroll
      for (int r = 0; r < 4; ++r){
        float m = c[0][nt][r];
#pragma unroll
        for (int b = 1; b < 8; ++b) m = fmaxf(m, c[b][nt][r]);
        float e[8], s = 0.f;
#pragma unroll
        for (int b = 0; b < 8; ++b){ e[b] = __builtin_amdgcn_exp2f((c[b][nt][r] - m)*RSCALE_LG); s += e[b]; }
        float ri = __builtin_amdgcn_rcpf(s);
#pragma unroll
        for (int b = 0; b < 8; ++b)
          if (q0 + r < lenv[b]) cs[b][nt] += e[b]*ri;
      }
    }
#pragma unroll
    for (int b = 0; b < 8; ++b)
#pragma unroll
      for (int nt = 0; nt < 4; ++nt){
        float v = cs[b][nt];
        v += __shfl_xor(v, 16); v += __shfl_xor(v, 32);
        if (l < 16) atomicAdd(&cbuf[b][nt*16 + l], v);
      }
  }
  __syncthreads();
  if (tid < 256){
    for (int i = tid; i < 512; i += 256)
      atomicAdd(&colsum[(size_t)(i >> 6)*2048 + kt*64 + (i & 63)], cbuf[i >> 6][i & 63]);
  }
}

// ---------------- fused dispatch A: rec layer0 + qkv + conv ----------------
__global__ __launch_bounds__(512, 2) void k_fusedA(const int* lens, const float* convb, char* ws,
    const float* whh0, u16* outH1)
{
  __shared__ __align__(16) char smem[90112];   // 88KB -> 1 block/CU, protects rec CUs
  const int bid = blockIdx.x;
  if (bid < 16){
    rec_block(smem, (const float*)(ws + OFS_XG), whh0, (const float*)(ws + OFS_BHHN),
              lens, outH1, bid >> 3, bid & 7);
    return;
  }
  int r = bid - 16;
  if (r < 768){
    int z = r >> 8, rem = r & 255, b = rem >> 5, tt = rem & 31;
    qkv_role(smem, ws, tt, b, z);
    return;
  }
  r -= 768;  // [0,256): conv
  conv_role(smem, lens, convb, ws, r & 31, r >> 5);
}

// ---------------- fused dispatch B: rec layer1 + scores ----------------
__global__ __launch_bounds__(512, 2) void k_fusedB(const int* lens, char* ws,
    const float* whh1, u16* outENC)
{
  __shared__ __align__(16) char smem[90112];
  const int bid = blockIdx.x;
  if (bid < 16){
    rec_block(smem, (const float*)(ws + OFS_XG), whh1, (const float*)(ws + OFS_BHHN) + 2*128,
              lens, outENC, bid >> 3, bid & 7);
    return;
  }
  int r = bid - 16;           // [0,1024): scores
  scores_role(smem, lens, ws, r & 31, r >> 5);
}

// ---------------- sa: 64-way split, atomicAdd into SA (zeroed in prep) ----------------
__global__ __launch_bounds__(256) void k_sa(char* ws){
  const int b = blockIdx.x >> 3, kc = blockIdx.x & 7;
  const int d = threadIdx.x;
  const float* cs = (const float*)(ws + OFS_CS) + (size_t)b*2048 + kc*256;
  const u16* V = (const u16*)(ws + OFS_V) + ((size_t)(b*2048 + kc*256))*256;
  float a0 = 0.f, a1 = 0.f, a2 = 0.f, a3 = 0.f;
  for (int k = 0; k < 256; k += 4){
    a0 += cs[k + 0]*bf2f(V[(size_t)(k + 0)*256 + d]);
    a1 += cs[k + 1]*bf2f(V[(size_t)(k + 1)*256 + d]);
    a2 += cs[k + 2]*bf2f(V[(size_t)(k + 2)*256 + d]);
    a3 += cs[k + 3]*bf2f(V[(size_t)(k + 3)*256 + d]);
  }
  atomicAdd(&((float*)(ws + OFS_SA))[b*256 + d], (a0 + a1) + (a2 + a3));
}

// ---------------- encres: fused encW-tile GEMM + tanh-reduce -> res (no ENCW round-trip) ----
// Block (tt,b): compute encW[64 rows][256 h] tile in registers (enc @ Wa2^T), then for
// x in {0,1}: res[row] = sum_h tanh(encW[row][h] + sw[x][h]) * vt[h]  (reduce over nt in
// thread, then over cl lanes via shfl). Eliminates the 16.8MB ENCW write + 33.6MB read.
__global__ __launch_bounds__(256, 1) void k_encres(const int* lens, const float* WaW,
    const float* Wab, const float* VTw, const float* VTb, char* ws){
  const int tt = blockIdx.x, b = blockIdx.y;
  const u16* in = (const u16*)(ws + OFS_ENC);
  const u16* wmat = (const u16*)(ws + OFS_WA2);
  const float* tm = (const float*)(ws + OFS_TM) + b*128;
  const float* sa = (const float*)(ws + OFS_SA) + b*256;
  float* res = (float*)(ws + OFS_RES);
  __shared__ __align__(16) u16 sA[64][264];
  __shared__ float sw[2][256];
  __shared__ float vt[256];
  const int tid = threadIdx.x, w = tid >> 6, l = tid & 63, rowg = l >> 4, cl = l & 15;
  {
    const int h = tid;
    float a0 = Wab[h], a1 = Wab[h];
    const float* wr = WaW + (size_t)h*512;
    for (int jj = 0; jj < 128; ++jj)
      a0 += tm[jj]*(1.f/2048.f)*(wr[2*jj] + wr[2*jj + 1]);
    for (int k = 0; k < 256; ++k) a1 += sa[k]*wr[k];
    sw[0][h] = a0; sw[1][h] = a1; vt[h] = VTw[h];
  }
  for (int idx = tid; idx < 64*32; idx += 256){
    int row = idx >> 5, chn = idx & 31;
    int t = tt*64 + row;
    *(u16x8*)&sA[row][chn*8] = *(const u16x8*)(in + ((size_t)(b*2048 + t))*256 + chn*8);
  }
  __syncthreads();
  f32x4 acc[16];
#pragma unroll
  for (int nt = 0; nt < 16; ++nt) acc[nt] = f32x4{0.f,0.f,0.f,0.f};
#pragma unroll
  for (int kk = 0; kk < 8; ++kk){
    short8 a = *(const short8*)&sA[w*16 + cl][kk*32 + rowg*8];
#pragma unroll
    for (int nt = 0; nt < 16; ++nt){
      short8 bb = *(const short8*)(wmat + (size_t)(nt*16 + cl)*256 + kk*32 + rowg*8);
      acc[nt] = MFMA16(a, bb, acc[nt]);
    }
  }
  const int lenb = lens[b];
  const float vtb = VTb[0];
#pragma unroll
  for (int x = 0; x < 2; ++x){
#pragma unroll
    for (int r = 0; r < 4; ++r){
      float racc = 0.f;
#pragma unroll
      for (int nt = 0; nt < 16; ++nt){
        float uarg = acc[nt][r] + sw[x][nt*16 + cl];
        float th = 1.f - 2.f*__builtin_amdgcn_rcpf(1.f + __builtin_amdgcn_exp2f(uarg*TWOLOG2E_C));
        racc += th*vt[nt*16 + cl];
      }
      racc += __shfl_xor(racc, 1);
      racc += __shfl_xor(racc, 2);
      racc += __shfl_xor(racc, 4);
      racc += __shfl_xor(racc, 8);
      if (cl == 0){
        int row = tt*64 + w*16 + rowg*4 + r;
        res[((size_t)b*2 + x)*2048 + row] = (row < lenb) ? (racc + vtb) : 0.f;
      }
    }
  }
}

// ---------------- softmax over L + weighted enc sum -> d1/d2 (4-way l-split) ----------------
__global__ __launch_bounds__(256) void k_attnfin(char* ws){
  const int b = blockIdx.x, x = blockIdx.y, ch = blockIdx.z;
  const float* res = (const float*)(ws + OFS_RES) + ((size_t)b*2 + x)*2048;
  const u16* enc = (const u16*)(ws + OFS_ENC);
  float* dvec = (float*)(ws + OFS_DV);
  __shared__ float sv[2048];
  __shared__ float red[8];
  const int tid = threadIdx.x;
  float m = -3.0e38f;
  for (int i = tid; i < 2048; i += 256){ float v = res[i]; sv[i] = v; m = fmaxf(m, v); }
#pragma unroll
  for (int o = 1; o < 64; o <<= 1) m = fmaxf(m, __shfl_xor(m, o));
  if ((tid & 63) == 0) red[tid >> 6] = m;
  __syncthreads();
  m = fmaxf(fmaxf(red[0], red[1]), fmaxf(red[2], red[3]));
  __syncthreads();
  float s = 0.f;
  for (int i = tid; i < 2048; i += 256){ float e = __builtin_amdgcn_exp2f((sv[i] - m)*LOG2E_C); sv[i] = e; s += e; }
#pragma unroll
  for (int o = 1; o < 64; o <<= 1) s += __shfl_xor(s, o);
  if ((tid & 63) == 0) red[tid >> 6] = s;
  __syncthreads();
  const float S = red[0] + red[1] + red[2] + red[3];
  const float ri = 1.0f/S;
  const int h = tid;
  const int l0b = ch*512;
  float a0 = 0.f, a1 = 0.f, a2 = 0.f, a3 = 0.f;
  for (int l0 = l0b; l0 < l0b + 512; l0 += 4){
    a0 += sv[l0 + 0]*bf2f(enc[((size_t)(b*2048 + l0 + 0))*256 + h]);
    a1 += sv[l0 + 1]*bf2f(enc[((size_t)(b*2048 + l0 + 1))*256 + h]);
    a2 += sv[l0 + 2]*bf2f(enc[((size_t)(b*2048 + l0 + 2))*256 + h]);
    a3 += sv[l0 + 3]*bf2f(enc[((size_t)(b*2048 + l0 + 3))*256 + h]);
  }
  atomicAdd(&dvec[((size_t)b*2 + x)*256 + h], ((a0 + a1) + (a2 + a3))*ri);
}

// ---------------- final FC ----------------
__global__ __launch_bounds__(64) void k_final(const float* fcw, const float* fcb, char* ws, float* outp){
  const int i = threadIdx.x;
  if (i >= 48) return;
  const int b = i/6, o = i%6;
  const float* dv = (const float*)(ws + OFS_DV);
  float acc = fcb[o];
  for (int h = 0; h < 256; ++h)
    acc += 0.5f*(dv[((size_t)b*2 + 0)*256 + h] + dv[((size_t)b*2 + 1)*256 + h])*fcw[o*256 + h];
  outp[i] = acc;
}

// ---------------- host ----------------
extern "C" void kernel_launch(void* const* d_in, const int* in_sizes, int n_in,
                              void* d_out, int out_size, void* d_ws, size_t ws_size,
                              hipStream_t stream)
{
  const int* tok    = (const int*)d_in[0];
  const int* lens   = (const int*)d_in[1];
  const float* embed= (const float*)d_in[2];
  const float* wih0 = (const float*)d_in[3];
  const float* whh0 = (const float*)d_in[4];
  const float* bih0 = (const float*)d_in[5];
  const float* bhh0 = (const float*)d_in[6];
  const float* wih1 = (const float*)d_in[7];
  const float* whh1 = (const float*)d_in[8];
  const float* bih1 = (const float*)d_in[9];
  const float* bhh1 = (const float*)d_in[10];
  const float* convw= (const float*)d_in[11];
  const float* convb= (const float*)d_in[12];
  const float* WaW  = (const float*)d_in[13];
  const float* Wab  = (const float*)d_in[14];
  const float* VTw  = (const float*)d_in[15];
  const float* VTb  = (const float*)d_in[16];
  const float* Qw   = (const float*)d_in[17];
  const float* Kw   = (const float*)d_in[18];
  const float* Vw   = (const float*)d_in[19];
  const float* fcw  = (const float*)d_in[20];
  const float* fcb  = (const float*)d_in[21];
  char* ws = (char*)d_ws;
  float* outp = (float*)d_out;

  hipLaunchKernelGGL(k_prep, dim3(1398), dim3(256), 0, stream,
      tok, lens, embed, wih0, wih1, bih0, bhh0, bih1, bhh1, convw, WaW, Qw, Kw, Vw, ws);
  hipLaunchKernelGGL((k_xg<128>), dim3(32,8,2), dim3(256), 0, stream, lens, ws);
  hipLaunchKernelGGL(k_fusedA, dim3(16 + 768 + 256), dim3(512), 0, stream,
      lens, convb, ws, whh0, (u16*)(ws + OFS_H1));
  hipLaunchKernelGGL((k_xg<256>), dim3(32,8,2), dim3(256), 0, stream, lens, ws);
  hipLaunchKernelGGL(k_fusedB, dim3(16 + 1024), dim3(512), 0, stream,
      lens, ws, whh1, (u16*)(ws + OFS_ENC));
  hipLaunchKernelGGL(k_sa, dim3(64), dim3(256), 0, stream, ws);
  hipLaunchKernelGGL(k_encres, dim3(32,8), dim3(256), 0, stream, lens, WaW, Wab, VTw, VTb, ws);
  hipLaunchKernelGGL(k_attnfin, dim3(8,2,4), dim3(256), 0, stream, ws);
  hipLaunchKernelGGL(k_final, dim3(1), dim3(64), 0, stream, fcw, fcb, ws, outp);
  (void)in_sizes; (void)n_in; (void)out_size; (void)ws_size;
}

// Round 10
// 1703.806 us; speedup vs baseline: 1.1327x; 1.0024x over previous
//
#include <hip/hip_runtime.h>
#include <stdint.h>

typedef unsigned short u16;
typedef unsigned int u32;
typedef __attribute__((ext_vector_type(8))) short short8;
typedef __attribute__((ext_vector_type(8))) u16 u16x8;
typedef __attribute__((ext_vector_type(4))) float f32x4;
typedef __attribute__((ext_vector_type(2))) float f32x2;
typedef __attribute__((ext_vector_type(2))) u32 u32x2;

#define DEVINL static __device__ __forceinline__

#if !__has_builtin(__builtin_amdgcn_exp2f)
#define __builtin_amdgcn_exp2f(x) exp2f(x)
#endif
#if !__has_builtin(__builtin_amdgcn_rcpf)
#define __builtin_amdgcn_rcpf(x) (1.0f/(x))
#endif

#define MFMA16(a, b, c) __builtin_amdgcn_mfma_f32_16x16x32_bf16((a), (b), (c), 0, 0, 0)

constexpr float LOG2E_C    = 1.4426950408889634f;
constexpr float TWOLOG2E_C = 2.8853900817779268f;
constexpr float RSCALE_LG  = 1.4426950408889634f / 11.313708498984761f; // log2e / sqrt(128)

// ---------------- workspace layout (bytes) ----------------
constexpr size_t A256(size_t x){ return (x + 255) & ~(size_t)255; }
constexpr size_t OFS_EMB   = 0;                                         // u16 [8][2051][128] unmasked emb
constexpr size_t OFS_PAD   = A256(OFS_EMB  + (size_t)8*2051*128*2);     // (unused now: masked inline)
constexpr size_t OFS_X1    = A256(OFS_PAD  + (size_t)8*2048*128*2);     // (unused)
constexpr size_t OFS_X2    = A256(OFS_X1   + (size_t)8*2050*128*2);     // (unused)
constexpr size_t OFS_QKVW  = A256(OFS_X2   + (size_t)8*2049*128*2);     // u16 [3][256][128] folded
constexpr size_t OFS_WA2   = A256(OFS_QKVW + (size_t)3*256*128*2);      // u16 [256][256]
constexpr size_t OFS_CONVW = A256(OFS_WA2  + (size_t)256*256*2);        // u16 [3][128][256]
constexpr size_t OFS_WIH0  = A256(OFS_CONVW+ (size_t)3*128*256*2);      // u16 [2][384][128]
constexpr size_t OFS_WIH1  = A256(OFS_WIH0 + (size_t)2*384*128*2);      // u16 [2][384][256]
constexpr size_t OFS_BIASX = A256(OFS_WIH1 + (size_t)2*384*256*2);      // f32 [2][2][384] scaled biases
constexpr size_t OFS_BHHN  = A256(OFS_BIASX+ (size_t)2*2*384*4);        // f32 [2][2][128] 2log2e*bhh_n
constexpr size_t OFS_Q     = A256(OFS_BHHN + (size_t)2*2*128*4);        // u16 [8][2048][256]
constexpr size_t OFS_K     = A256(OFS_Q    + (size_t)8*2048*256*2);
constexpr size_t OFS_V     = A256(OFS_K    + (size_t)8*2048*256*2);
constexpr size_t OFS_CS    = A256(OFS_V    + (size_t)8*2048*256*2);     // f32 [8][2048] colsum
constexpr size_t OFS_TM    = A256(OFS_CS   + (size_t)8*2048*4);         // f32 [8][128] tmean sums
constexpr size_t OFS_XG    = A256(OFS_TM   + (size_t)8*128*4);          // f32 [2][2048][8][384]
constexpr size_t OFS_H1    = A256(OFS_XG   + (size_t)2*2048*8*384*4);   // u16 [8][2048][256]
constexpr size_t OFS_ENC   = A256(OFS_H1   + (size_t)8*2048*256*2);     // u16 [8][2048][256]
constexpr size_t OFS_ENCW  = A256(OFS_ENC  + (size_t)8*2048*256*2);     // f32 (unused now)
constexpr size_t OFS_SA    = A256(OFS_ENCW + (size_t)8*2048*256*4);     // f32 [8][256]
constexpr size_t OFS_RES   = A256(OFS_SA   + (size_t)8*256*4);          // f32 [8][2][2048]
constexpr size_t OFS_DV    = A256(OFS_RES  + (size_t)8*2*2048*4);       // f32 [8][2][256]

// ---------------- helpers ----------------
DEVINL u16 f2bf(float f){
  u32 u = __builtin_bit_cast(u32, f);
  u32 r = (u + 0x7FFFu + ((u >> 16) & 1u)) >> 16;
  return (u16)r;
}
DEVINL float bf2f(u16 s){ return __builtin_bit_cast(float, (u32)s << 16); }

DEVINL short8 ld8cvt(const float* p, float sc){
  short8 o;
#pragma unroll
  for (int e = 0; e < 8; ++e) o[e] = (short)f2bf(p[e]*sc);
  return o;
}

DEVINL u32 cvtpk(float lo, float hi){
  u32 r;
  asm("v_cvt_pk_bf16_f32 %0, %1, %2" : "=v"(r) : "v"(lo), "v"(hi));
  return r;
}

DEVINL float sel4(const f32x4 v, int rr){
  float a = (rr & 1) ? v[1] : v[0];
  float bq = (rr & 1) ? v[3] : v[2];
  return (rr & 2) ? bq : a;
}

// ---------------- prep: vectorized gathers (8 elems/thread), weight conversions, zeroing ----------------
__global__ __launch_bounds__(256) void k_prep(
    const int* tok, const int* lens, const float* embed,
    const float* wih0, const float* wih1,
    const float* bih0, const float* bhh0, const float* bih1, const float* bhh1,
    const float* convw, const float* WaW, const float* Qw, const float* Kw, const float* Vw,
    char* ws)
{
  u16* emb_bf   = (u16*)(ws + OFS_EMB);
  u16* qkvw     = (u16*)(ws + OFS_QKVW);
  u16* wa2      = (u16*)(ws + OFS_WA2);
  u16* convw_bf = (u16*)(ws + OFS_CONVW);
  u16* wih0_bf  = (u16*)(ws + OFS_WIH0);
  u16* wih1_bf  = (u16*)(ws + OFS_WIH1);
  float* biasx  = (float*)(ws + OFS_BIASX);
  float* bhhn   = (float*)(ws + OFS_BHHN);
  float* colsum = (float*)(ws + OFS_CS);
  float* tmean  = (float*)(ws + OFS_TM);
  float* dvec   = (float*)(ws + OFS_DV);
  float* sabuf  = (float*)(ws + OFS_SA);
  const int V0 = 8*2051*16;     // emb, 8 elems per item
  const int V1 = 3*256*16;      // qkvw
  const int V2 = 256*32;        // wa2
  const int V3 = 3*128*32;      // convw
  const int V4 = 2*384*16;      // wih0
  const int V5 = 2*384*32;      // wih1
  const int V6 = 2*2*384 + 2*2*128;                 // biasx + bhhn (scalar)
  const int V7 = 8*2048 + 8*128 + 8*2*256 + 8*256;  // zeros: colsum, tmean, dvec, sa
  const int TOT = V0+V1+V2+V3+V4+V5+V6+V7;
  for (int i = blockIdx.x*256 + threadIdx.x; i < TOT; i += gridDim.x*256){
    int j = i;
    if (j < V0){
      int b = j / (2051*16); int r = j - b*(2051*16); int t = r >> 4, chn = r & 15;
      const float* ep = embed + (size_t)tok[b*4000 + t]*128 + chn*8;
      u16x8 pk;
#pragma unroll
      for (int e = 0; e < 8; ++e) pk[e] = f2bf(ep[e]);
      *(u16x8*)(emb_bf + ((size_t)(b*2051 + t))*128 + chn*8) = pk;
      continue;
    }
    j -= V0;
    if (j < V1){
      int z = j / (256*16); int r = j - z*(256*16); int o = r >> 4, chn = r & 15;
      const float* W = (z == 0) ? Qw : (z == 1) ? Kw : Vw;
      const float* p0 = W + (size_t)o*256 + chn*8;
      u16x8 pk;
#pragma unroll
      for (int e = 0; e < 8; ++e) pk[e] = f2bf(p0[e] + p0[128 + e]);
      *(u16x8*)(qkvw + ((size_t)z*256 + o)*128 + chn*8) = pk;
      continue;
    }
    j -= V1;
    if (j < V2){
      int h = j >> 5, chn = j & 31;
      const float* p = WaW + (size_t)h*512 + 256 + chn*8;
      u16x8 pk;
#pragma unroll
      for (int e = 0; e < 8; ++e) pk[e] = f2bf(p[e]);
      *(u16x8*)(wa2 + (size_t)h*256 + chn*8) = pk;
      continue;
    }
    j -= V2;
    if (j < V3){
      int ly = j / (128*32); int r = j - ly*(128*32); int o = r >> 5, chn = r & 31;
      u16x8 pk;
#pragma unroll
      for (int e = 0; e < 8; ++e){
        int k2 = chn*8 + e; int i2 = k2 & 127, kap = k2 >> 7;
        pk[e] = f2bf(convw[((size_t)(ly*128 + o)*128 + i2)*2 + kap]);
      }
      *(u16x8*)(convw_bf + ((size_t)(ly*128 + o))*256 + chn*8) = pk;
      continue;
    }
    j -= V3;
    if (j < V4){
      const float* p = wih0 + (size_t)j*8;
      u16x8 pk;
#pragma unroll
      for (int e = 0; e < 8; ++e) pk[e] = f2bf(p[e]);
      *(u16x8*)(wih0_bf + (size_t)j*8) = pk;
      continue;
    }
    j -= V4;
    if (j < V5){
      const float* p = wih1 + (size_t)j*8;
      u16x8 pk;
#pragma unroll
      for (int e = 0; e < 8; ++e) pk[e] = f2bf(p[e]);
      *(u16x8*)(wih1_bf + (size_t)j*8) = pk;
      continue;
    }
    j -= V5;
    if (j < V6){
      if (j < 1536){
        int ly = j / 768; int r = j - ly*768; int d = r / 384, g = r % 384;
        float bi = (ly ? bih1 : bih0)[d*384 + g];
        float bh = (ly ? bhh1 : bhh0)[d*384 + g];
        biasx[j] = (g < 256) ? (-LOG2E_C*(bi + bh)) : (TWOLOG2E_C*bi);
      } else {
        int j2 = j - 1536; int ly = j2 >> 8; int r = j2 & 255; int d = r >> 7, jj = r & 127;
        bhhn[j2] = TWOLOG2E_C*((ly ? bhh1 : bhh0)[d*384 + 256 + jj]);
      }
      continue;
    }
    j -= V6;
    if (j < 8*2048){ colsum[j] = 0.f; continue; }
    j -= 8*2048;
    if (j < 8*128){ tmean[j] = 0.f; continue; }
    j -= 8*128;
    if (j < 8*2*256){ dvec[j] = 0.f; continue; }
    sabuf[j - 8*2*256] = 0.f;
  }
}

// ---------------- xg = in @ Wih^T, scaled/biased for exp2-based gates ----------------
// KIN==128 reads EMB (row stride 2051) with inline pad-masking; KIN==256 reads H1
// (already zero past lens[b]).
template<int KIN>
__global__ __launch_bounds__(256, 1) void k_xg(const int* lens, char* ws){
  const int tt = blockIdx.x, b = blockIdx.y, dir = blockIdx.z;
  constexpr int LAYER = (KIN == 128) ? 0 : 1;
  constexpr int ROWS = (KIN == 128) ? 2051 : 2048;
  const u16* in = (KIN == 128) ? (const u16*)(ws + OFS_EMB) : (const u16*)(ws + OFS_H1);
  const u16* wmat = ((KIN == 128) ? (const u16*)(ws + OFS_WIH0) : (const u16*)(ws + OFS_WIH1))
                    + (size_t)dir*384*KIN;
  const float* biasx = (const float*)(ws + OFS_BIASX) + (LAYER*2 + dir)*384;
  float* xg = (float*)(ws + OFS_XG) + (size_t)dir*2048*3072;
  const int lenb = lens[b];
  __shared__ __align__(16) u16 sA[64][KIN + 8];
  constexpr int CH = KIN/8;
  const int tid = threadIdx.x, w = tid >> 6, l = tid & 63, rowg = l >> 4, cl = l & 15;
  for (int idx = tid; idx < 64*CH; idx += 256){
    int row = idx / CH, chn = idx % CH;
    int t = tt*64 + row;
    int tr = dir ? ((t < lenb) ? (lenb - 1 - t) : t) : t;
    u16x8 v = *(const u16x8*)(in + ((size_t)(b*ROWS + tr))*KIN + chn*8);
    if (KIN == 128 && tr >= lenb){ u16x8 z = {0,0,0,0,0,0,0,0}; v = z; }
    *(u16x8*)&sA[row][chn*8] = v;
  }
  __syncthreads();
  f32x4 acc[24];
#pragma unroll
  for (int nt = 0; nt < 24; ++nt) acc[nt] = f32x4{0.f,0.f,0.f,0.f};
#pragma unroll
  for (int kk = 0; kk < KIN/32; ++kk){
    short8 a = *(const short8*)&sA[w*16 + cl][kk*32 + rowg*8];
#pragma unroll
    for (int nt = 0; nt < 24; ++nt){
      short8 bb = *(const short8*)(wmat + (size_t)(nt*16 + cl)*KIN + kk*32 + rowg*8);
      acc[nt] = MFMA16(a, bb, acc[nt]);
    }
  }
#pragma unroll
  for (int nt = 0; nt < 24; ++nt){
    const int g = nt*16 + cl;
    const float bx = biasx[g];
    const float sc = (nt < 16) ? -LOG2E_C : TWOLOG2E_C;
#pragma unroll
    for (int r = 0; r < 4; ++r){
      const int t = tt*64 + w*16 + rowg*4 + r;
      xg[((size_t)t*8 + b)*384 + g] = sc*acc[nt][r] + bx;
    }
  }
}

// ---------------- GRU recurrence block body (R4/R6-proven: depth-4 chains) ----------------
// setprio removed this round (R7 bundled it; isolated A/B via fusedA now).
DEVINL void rec_block(char* smem, const float* xg_all, const float* whh_all,
    const float* bhhn_all, const int* lens, u16* out, int dir, int b)
{
  const float* xg  = xg_all + (size_t)dir*2048*3072 + b*384;
  const float* whh = whh_all + (size_t)dir*384*128;
  const float* bnd = bhhn_all + dir*128;
  const int tid = threadIdx.x;
  const int u = tid >> 6, l = tid & 63;
  const int c = l & 15, q = l >> 4;
  const int rsel = c & 3;
  const int j = u*16 + q*4 + rsel;             // this lane's gate index within 128
  const bool writer = (c < 4);
  const bool dirb = (dir != 0);
  const int lenb = lens[b];

  u16 (*hbuf)[128] = (u16(*)[128])smem;        // [2][128]
  if (tid < 256) (&hbuf[0][0])[tid] = 0;

  short8 aR[4], aZ[4], aN[4];
#pragma unroll
  for (int kk = 0; kk < 4; ++kk){
    int k0 = kk*32 + q*8;
    int row = u*16 + c;
    aR[kk] = ld8cvt(whh + (size_t)(row)*128 + k0, -LOG2E_C);
    aZ[kk] = ld8cvt(whh + (size_t)(128 + row)*128 + k0, -LOG2E_C);
    aN[kk] = ld8cvt(whh + (size_t)(256 + row)*128 + k0, TWOLOG2E_C);
  }
  f32x4 bnU;
#pragma unroll
  for (int r = 0; r < 4; ++r) bnU[r] = bnd[u*16 + q*4 + r];

  const int offR = u*16 + q*4;          // float offset into xg[t] R section (Z at +128)
  const int offXN = 256 + j;            // this lane's XN scalar
  u16* outp = out + (size_t)b*2048*256 + dir*128 + j;
  float hp = 0.f;

#define LOAD_STAGE(T_, Rv, Zv, Xn) do {              \
    const float* pb_ = xg + (size_t)(T_)*3072;       \
    Rv = *(const f32x4*)(pb_ + offR);                \
    Zv = *(const f32x4*)(pb_ + offR + 128);          \
    Xn = pb_[offXN];                                 \
  } while (0)

#define REC_STEP(T_, PF_, CUR_, Rv, Zv, Xn) do {                                      \
    short8 bf0_ = *(const short8*)(&hbuf[CUR_][0] + (q*8 + 0*32));                    \
    short8 bf1_ = *(const short8*)(&hbuf[CUR_][0] + (q*8 + 1*32));                    \
    short8 bf2_ = *(const short8*)(&hbuf[CUR_][0] + (q*8 + 2*32));                    \
    short8 bf3_ = *(const short8*)(&hbuf[CUR_][0] + (q*8 + 3*32));                    \
    f32x4 cR_ = MFMA16(aR[0], bf0_, Rv);                                              \
    f32x4 cZ_ = MFMA16(aZ[0], bf0_, Zv);                                              \
    f32x4 cN_ = MFMA16(aN[0], bf0_, bnU);                                             \
    const float* pfb_ = xg + (size_t)(PF_)*3072;                                      \
    Rv = *(const f32x4*)(pfb_ + offR);                                                \
    Zv = *(const f32x4*)(pfb_ + offR + 128);                                          \
    float Xnew_ = pfb_[offXN];                                                        \
    cR_ = MFMA16(aR[1], bf1_, cR_);                                                   \
    cZ_ = MFMA16(aZ[1], bf1_, cZ_);                                                   \
    cN_ = MFMA16(aN[1], bf1_, cN_);                                                   \
    cR_ = MFMA16(aR[2], bf2_, cR_);                                                   \
    cZ_ = MFMA16(aZ[2], bf2_, cZ_);                                                   \
    cN_ = MFMA16(aN[2], bf2_, cN_);                                                   \
    cR_ = MFMA16(aR[3], bf3_, cR_);                                                   \
    cZ_ = MFMA16(aZ[3], bf3_, cZ_);                                                   \
    cN_ = MFMA16(aN[3], bf3_, cN_);                                                   \
    const bool v_ = (T_) < lenb;                                                      \
    float gR = sel4(cR_, rsel);                                                       \
    float gZ = sel4(cZ_, rsel);                                                       \
    float gN = sel4(cN_, rsel);                                                       \
    float Rg = __builtin_amdgcn_rcpf(1.f + __builtin_amdgcn_exp2f(gR));               \
    float Zg = __builtin_amdgcn_rcpf(1.f + __builtin_amdgcn_exp2f(gZ));               \
    float y  = Xn + Rg*gN;                                                            \
    float NN = 1.f - 2.f*__builtin_amdgcn_rcpf(1.f + __builtin_amdgcn_exp2f(y));      \
    float hn = NN + Zg*(hp - NN);                                                     \
    hp = hn;                                                                          \
    Xn = Xnew_;                                                                       \
    u32 pk_ = cvtpk(hn, hn);                                                          \
    if (writer){                                                                      \
      hbuf[(CUR_) ^ 1][j] = (u16)pk_;                                                 \
      int to_ = dirb ? (v_ ? (lenb - 1 - (T_)) : (T_)) : (T_);                        \
      outp[(size_t)to_*256] = v_ ? (u16)pk_ : (u16)0;                                 \
    }                                                                                 \
    asm volatile("s_waitcnt lgkmcnt(0)" ::: "memory");                                \
    __builtin_amdgcn_s_barrier();                                                     \
  } while (0)

  f32x4 R0v, Z0v; float X0;
  f32x4 R1v, Z1v; float X1;
  f32x4 R2v, Z2v; float X2;
  f32x4 R3v, Z3v; float X3;
  __syncthreads();
  LOAD_STAGE(0, R0v, Z0v, X0);
  LOAD_STAGE(1, R1v, Z1v, X1);
  LOAD_STAGE(2, R2v, Z2v, X2);
  LOAD_STAGE(3, R3v, Z3v, X3);
  for (int t = 0; t < 2048; t += 4){
    int p4 = (t + 4 < 2048) ? (t + 4) : 2047;
    int p5 = (t + 5 < 2048) ? (t + 5) : 2047;
    int p6 = (t + 6 < 2048) ? (t + 6) : 2047;
    int p7 = (t + 7 < 2048) ? (t + 7) : 2047;
    REC_STEP(t + 0, p4, 0, R0v, Z0v, X0);
    REC_STEP(t + 1, p5, 1, R1v, Z1v, X1);
    REC_STEP(t + 2, p6, 0, R2v, Z2v, X2);
    REC_STEP(t + 3, p7, 1, R3v, Z3v, X3);
  }
#undef LOAD_STAGE
#undef REC_STEP
}

// ---------------- qkv role (256 active threads; barriers by all 512) ----------------
// Reads EMB with inline pad-masking (t >= lens[b] -> 0).
DEVINL void qkv_role(char* smem, char* ws, const int* lens, int tt, int b, int z){
  const u16* in = (const u16*)(ws + OFS_EMB);
  const u16* wmat = (const u16*)(ws + OFS_QKVW) + (size_t)z*256*128;
  u16* out = (u16*)(ws + ((z == 0) ? OFS_Q : (z == 1) ? OFS_K : OFS_V));
  u16 (*sA)[136] = (u16(*)[136])smem;
  const int tid = threadIdx.x;
  const int lenb = lens[b];
  if (tid < 256){
    for (int idx = tid; idx < 64*16; idx += 256){
      int row = idx >> 4, chn = idx & 15;
      int t = tt*64 + row;
      u16x8 v = *(const u16x8*)(in + ((size_t)(b*2051 + t))*128 + chn*8);
      if (t >= lenb){ u16x8 zz = {0,0,0,0,0,0,0,0}; v = zz; }
      *(u16x8*)&sA[row][chn*8] = v;
    }
  }
  __syncthreads();
  if (tid < 256){
    const int w = tid >> 6, l = tid & 63, rowg = l >> 4, cl = l & 15;
    f32x4 acc[16];
#pragma unroll
    for (int nt = 0; nt < 16; ++nt) acc[nt] = f32x4{0.f,0.f,0.f,0.f};
#pragma unroll
    for (int kk = 0; kk < 4; ++kk){
      short8 a = *(const short8*)&sA[w*16 + cl][kk*32 + rowg*8];
#pragma unroll
      for (int nt = 0; nt < 16; ++nt){
        short8 bb = *(const short8*)(wmat + (size_t)(nt*16 + cl)*128 + kk*32 + rowg*8);
        acc[nt] = MFMA16(a, bb, acc[nt]);
      }
    }
#pragma unroll
    for (int nt = 0; nt < 16; ++nt){
      int o = nt*16 + cl;
#pragma unroll
      for (int r = 0; r < 4; ++r){
        int t = tt*64 + w*16 + rowg*4 + r;
        out[((size_t)(b*2048 + t))*256 + o] = f2bf(acc[nt][r]);
      }
    }
  }
}

// ---------------- conv role: 3 layers fused in LDS with halo; writes only tmean ----------------
DEVINL void conv_layer_pass(u16 (*bi)[136], u16 (*bo)[136], const u16* wm, const float* bias,
                            int OUT_R, int w, int rowg, int cl){
#pragma unroll
  for (int pass = 0; pass < 2; ++pass){
    if (pass == 1 && !(w == 0 && OUT_R > 64)) break;
    const int rt = (pass == 0) ? w : 4;
    f32x4 acc[8];
#pragma unroll
    for (int nt = 0; nt < 8; ++nt) acc[nt] = f32x4{0.f,0.f,0.f,0.f};
#pragma unroll
    for (int kk = 0; kk < 8; ++kk){
      const int rofs = (kk >= 4) ? 1 : 0;
      short8 a = *(const short8*)&bi[rt*16 + cl + rofs][(kk & 3)*32 + rowg*8];
#pragma unroll
      for (int nt = 0; nt < 8; ++nt){
        short8 bb = *(const short8*)(wm + (size_t)(nt*16 + cl)*256 + kk*32 + rowg*8);
        acc[nt] = MFMA16(a, bb, acc[nt]);
      }
    }
#pragma unroll
    for (int nt = 0; nt < 8; ++nt){
      int o = nt*16 + cl;
      float bv = bias[o];
#pragma unroll
      for (int r = 0; r < 4; ++r){
        int ro = rt*16 + rowg*4 + r;
        if (ro < OUT_R) bo[ro][o] = f2bf(fmaxf(acc[nt][r] + bv, 0.f));
      }
    }
  }
}

DEVINL void conv_role(char* smem, const int* lens, const float* convb, char* ws, int tt, int b){
  const u16* emb = (const u16*)(ws + OFS_EMB);
  const u16* cw  = (const u16*)(ws + OFS_CONVW);
  float* tmean = (float*)(ws + OFS_TM);
  u16 (*bufA)[136] = (u16(*)[136])smem;                     // 82 rows
  u16 (*bufB)[136] = (u16(*)[136])(smem + 82*136*2);        // 82 rows
  const int tid = threadIdx.x;
  const int w = tid >> 6, l = tid & 63, rowg = l >> 4, cl = l & 15;
  if (tid < 256){
    for (int idx = tid; idx < 67*16; idx += 256){
      int row = idx >> 4, chn = idx & 15;
      *(u16x8*)&bufA[row][chn*8] = *(const u16x8*)(emb + ((size_t)(b*2051 + tt*64 + row))*128 + chn*8);
    }
  }
  __syncthreads();
  if (tid < 256) conv_layer_pass(bufA, bufB, cw + (size_t)0*128*256, convb + 0,   66, w, rowg, cl);
  __syncthreads();
  if (tid < 256) conv_layer_pass(bufB, bufA, cw + (size_t)1*128*256, convb + 128, 65, w, rowg, cl);
  __syncthreads();
  if (tid < 256){
    const int lenb = lens[b];
    const u16* wm = cw + (size_t)2*128*256;
    f32x4 acc[8];
#pragma unroll
    for (int nt = 0; nt < 8; ++nt) acc[nt] = f32x4{0.f,0.f,0.f,0.f};
#pragma unroll
    for (int kk = 0; kk < 8; ++kk){
      const int rofs = (kk >= 4) ? 1 : 0;
      short8 a = *(const short8*)&bufA[w*16 + cl + rofs][(kk & 3)*32 + rowg*8];
#pragma unroll
      for (int nt = 0; nt < 8; ++nt){
        short8 bb = *(const short8*)(wm + (size_t)(nt*16 + cl)*256 + kk*32 + rowg*8);
        acc[nt] = MFMA16(a, bb, acc[nt]);
      }
    }
#pragma unroll
    for (int nt = 0; nt < 8; ++nt){
      int o = nt*16 + cl;
      float bias = convb[2*128 + o];
      float s = 0.f;
#pragma unroll
      for (int r = 0; r < 4; ++r){
        int t = tt*64 + w*16 + rowg*4 + r;
        if (t < lenb) s += fmaxf(acc[nt][r] + bias, 0.f);
      }
      s += __shfl_xor(s, 16); s += __shfl_xor(s, 32);
      if (l < 16) atomicAdd(&tmean[b*128 + o], s);
    }
  }
}

// ---------------- scores role (256 active threads; barriers by all 512) ----------------
DEVINL void scores_role(char* smem, const int* lens, char* ws, int kt, int qt){
  const u16* Qp = (const u16*)(ws + OFS_Q);
  const u16* Kp = (const u16*)(ws + OFS_K);
  float* colsum = (float*)(ws + OFS_CS);
  u16 (*sQ)[264] = (u16(*)[264])smem;                       // 64x264
  u16 (*sK)[264] = (u16(*)[264])(smem + 64*264*2);
  float (*cbuf)[64] = (float(*)[64])(smem + 2*64*264*2);    // 8x64
  const int tid = threadIdx.x, w = tid >> 6, l = tid & 63, rowg = l >> 4, cl = l & 15;
  if (tid < 256)
    for (int i = tid; i < 512; i += 256) cbuf[i >> 6][i & 63] = 0.f;
  f32x4 c[8][4];
#pragma unroll
  for (int b = 0; b < 8; ++b)
#pragma unroll
    for (int nt = 0; nt < 4; ++nt) c[b][nt] = f32x4{0.f,0.f,0.f,0.f};
#pragma unroll
  for (int b = 0; b < 8; ++b){
    __syncthreads();
    if (tid < 256){
      for (int idx = tid; idx < 4096; idx += 256){
        int which = idx >> 11, row = (idx >> 5) & 63, ch = idx & 31;
        if (which){
          *(u16x8*)&sK[row][ch*8] = *(const u16x8*)(Kp + ((size_t)(b*2048 + kt*64 + row))*256 + ch*8);
        } else {
          *(u16x8*)&sQ[row][ch*8] = *(const u16x8*)(Qp + ((size_t)(b*2048 + qt*64 + row))*256 + ch*8);
        }
      }
    }
    __syncthreads();
    if (tid < 256){
#pragma unroll
      for (int kk = 0; kk < 8; ++kk){
        short8 a = *(const short8*)&sQ[w*16 + cl][kk*32 + rowg*8];
#pragma unroll
        for (int nt = 0; nt < 4; ++nt){
          short8 bb = *(const short8*)&sK[nt*16 + cl][kk*32 + rowg*8];
          c[b][nt] = MFMA16(a, bb, c[b][nt]);
        }
      }
    }
  }
  if (tid < 256){
    int lenv[8];
#pragma unroll
    for (int b = 0; b < 8; ++b) lenv[b] = lens[b];
    const int q0 = qt*64 + w*16 + rowg*4;
    float cs[8][4];
#pragma unroll
    for (int b = 0; b < 8; ++b)
#pragma unroll
      for (int nt = 0; nt < 4; ++nt) cs[b][nt] = 0.f;
#pragma unroll
    for (int nt = 0; nt < 4; ++nt){
#pragma unroll
      for (int r = 0; r < 4; ++r){
        float m = c[0][nt][r];
#pragma unroll
        for (int b = 1; b < 8; ++b) m = fmaxf(m, c[b][nt][r]);
        float e[8], s = 0.f;
#pragma unroll
        for (int b = 0; b < 8; ++b){ e[b] = __builtin_amdgcn_exp2f((c[b][nt][r] - m)*RSCALE_LG); s += e[b]; }
        float ri = __builtin_amdgcn_rcpf(s);
#pragma unroll
        for (int b = 0; b < 8; ++b)
          if (q0 + r < lenv[b]) cs[b][nt] += e[b]*ri;
      }
    }
#pragma unroll
    for (int b = 0; b < 8; ++b)
#pragma unroll
      for (int nt = 0; nt < 4; ++nt){
        float v = cs[b][nt];
        v += __shfl_xor(v, 16); v += __shfl_xor(v, 32);
        if (l < 16) atomicAdd(&cbuf[b][nt*16 + l], v);
      }
  }
  __syncthreads();
  if (tid < 256){
    for (int i = tid; i < 512; i += 256)
      atomicAdd(&colsum[(size_t)(i >> 6)*2048 + kt*64 + (i & 63)], cbuf[i >> 6][i & 63]);
  }
}

// ---------------- fused dispatch A: rec layer0 + qkv + conv ----------------
__global__ __launch_bounds__(512, 2) void k_fusedA(const int* lens, const float* convb, char* ws,
    const float* whh0, u16* outH1)
{
  __shared__ __align__(16) char smem[90112];   // 88KB -> 1 block/CU, protects rec CUs
  const int bid = blockIdx.x;
  if (bid < 16){
    rec_block(smem, (const float*)(ws + OFS_XG), whh0, (const float*)(ws + OFS_BHHN),
              lens, outH1, bid >> 3, bid & 7);
    return;
  }
  int r = bid - 16;
  if (r < 768){
    int z = r >> 8, rem = r & 255, b = rem >> 5, tt = rem & 31;
    qkv_role(smem, ws, lens, tt, b, z);
    return;
  }
  r -= 768;  // [0,256): conv
  conv_role(smem, lens, convb, ws, r & 31, r >> 5);
}

// ---------------- fused dispatch B: rec layer1 + scores ----------------
__global__ __launch_bounds__(512, 2) void k_fusedB(const int* lens, char* ws,
    const float* whh1, u16* outENC)
{
  __shared__ __align__(16) char smem[90112];
  const int bid = blockIdx.x;
  if (bid < 16){
    rec_block(smem, (const float*)(ws + OFS_XG), whh1, (const float*)(ws + OFS_BHHN) + 2*128,
              lens, outENC, bid >> 3, bid & 7);
    return;
  }
  int r = bid - 16;           // [0,1024): scores
  scores_role(smem, lens, ws, r & 31, r >> 5);
}

// ---------------- sa: 64-way split, atomicAdd into SA (zeroed in prep) ----------------
__global__ __launch_bounds__(256) void k_sa(char* ws){
  const int b = blockIdx.x >> 3, kc = blockIdx.x & 7;
  const int d = threadIdx.x;
  const float* cs = (const float*)(ws + OFS_CS) + (size_t)b*2048 + kc*256;
  const u16* V = (const u16*)(ws + OFS_V) + ((size_t)(b*2048 + kc*256))*256;
  float a0 = 0.f, a1 = 0.f, a2 = 0.f, a3 = 0.f;
  for (int k = 0; k < 256; k += 4){
    a0 += cs[k + 0]*bf2f(V[(size_t)(k + 0)*256 + d]);
    a1 += cs[k + 1]*bf2f(V[(size_t)(k + 1)*256 + d]);
    a2 += cs[k + 2]*bf2f(V[(size_t)(k + 2)*256 + d]);
    a3 += cs[k + 3]*bf2f(V[(size_t)(k + 3)*256 + d]);
  }
  atomicAdd(&((float*)(ws + OFS_SA))[b*256 + d], (a0 + a1) + (a2 + a3));
}

// ---------------- encres: fused encW-tile GEMM + tanh-reduce -> res ----------------
__global__ __launch_bounds__(256, 1) void k_encres(const int* lens, const float* WaW,
    const float* Wab, const float* VTw, const float* VTb, char* ws){
  const int tt = blockIdx.x, b = blockIdx.y;
  const u16* in = (const u16*)(ws + OFS_ENC);
  const u16* wmat = (const u16*)(ws + OFS_WA2);
  const float* tm = (const float*)(ws + OFS_TM) + b*128;
  const float* sa = (const float*)(ws + OFS_SA) + b*256;
  float* res = (float*)(ws + OFS_RES);
  __shared__ __align__(16) u16 sA[64][264];
  __shared__ float sw[2][256];
  __shared__ float vt[256];
  const int tid = threadIdx.x, w = tid >> 6, l = tid & 63, rowg = l >> 4, cl = l & 15;
  {
    const int h = tid;
    float a0 = Wab[h], a1 = Wab[h];
    const float* wr = WaW + (size_t)h*512;
    for (int jj = 0; jj < 128; ++jj)
      a0 += tm[jj]*(1.f/2048.f)*(wr[2*jj] + wr[2*jj + 1]);
    for (int k = 0; k < 256; ++k) a1 += sa[k]*wr[k];
    sw[0][h] = a0; sw[1][h] = a1; vt[h] = VTw[h];
  }
  for (int idx = tid; idx < 64*32; idx += 256){
    int row = idx >> 5, chn = idx & 31;
    int t = tt*64 + row;
    *(u16x8*)&sA[row][chn*8] = *(const u16x8*)(in + ((size_t)(b*2048 + t))*256 + chn*8);
  }
  __syncthreads();
  f32x4 acc[16];
#pragma unroll
  for (int nt = 0; nt < 16; ++nt) acc[nt] = f32x4{0.f,0.f,0.f,0.f};
#pragma unroll
  for (int kk = 0; kk < 8; ++kk){
    short8 a = *(const short8*)&sA[w*16 + cl][kk*32 + rowg*8];
#pragma unroll
    for (int nt = 0; nt < 16; ++nt){
      short8 bb = *(const short8*)(wmat + (size_t)(nt*16 + cl)*256 + kk*32 + rowg*8);
      acc[nt] = MFMA16(a, bb, acc[nt]);
    }
  }
  const int lenb = lens[b];
  const float vtb = VTb[0];
#pragma unroll
  for (int x = 0; x < 2; ++x){
#pragma unroll
    for (int r = 0; r < 4; ++r){
      float racc = 0.f;
#pragma unroll
      for (int nt = 0; nt < 16; ++nt){
        float uarg = acc[nt][r] + sw[x][nt*16 + cl];
        float th = 1.f - 2.f*__builtin_amdgcn_rcpf(1.f + __builtin_amdgcn_exp2f(uarg*TWOLOG2E_C));
        racc += th*vt[nt*16 + cl];
      }
      racc += __shfl_xor(racc, 1);
      racc += __shfl_xor(racc, 2);
      racc += __shfl_xor(racc, 4);
      racc += __shfl_xor(racc, 8);
      if (cl == 0){
        int row = tt*64 + w*16 + rowg*4 + r;
        res[((size_t)b*2 + x)*2048 + row] = (row < lenb) ? (racc + vtb) : 0.f;
      }
    }
  }
}

// ---------------- softmax over L + weighted enc sum -> d1/d2 (4-way l-split) ----------------
__global__ __launch_bounds__(256) void k_attnfin(char* ws){
  const int b = blockIdx.x, x = blockIdx.y, ch = blockIdx.z;
  const float* res = (const float*)(ws + OFS_RES) + ((size_t)b*2 + x)*2048;
  const u16* enc = (const u16*)(ws + OFS_ENC);
  float* dvec = (float*)(ws + OFS_DV);
  __shared__ float sv[2048];
  __shared__ float red[8];
  const int tid = threadIdx.x;
  float m = -3.0e38f;
  for (int i = tid; i < 2048; i += 256){ float v = res[i]; sv[i] = v; m = fmaxf(m, v); }
#pragma unroll
  for (int o = 1; o < 64; o <<= 1) m = fmaxf(m, __shfl_xor(m, o));
  if ((tid & 63) == 0) red[tid >> 6] = m;
  __syncthreads();
  m = fmaxf(fmaxf(red[0], red[1]), fmaxf(red[2], red[3]));
  __syncthreads();
  float s = 0.f;
  for (int i = tid; i < 2048; i += 256){ float e = __builtin_amdgcn_exp2f((sv[i] - m)*LOG2E_C); sv[i] = e; s += e; }
#pragma unroll
  for (int o = 1; o < 64; o <<= 1) s += __shfl_xor(s, o);
  if ((tid & 63) == 0) red[tid >> 6] = s;
  __syncthreads();
  const float S = red[0] + red[1] + red[2] + red[3];
  const float ri = 1.0f/S;
  const int h = tid;
  const int l0b = ch*512;
  float a0 = 0.f, a1 = 0.f, a2 = 0.f, a3 = 0.f;
  for (int l0 = l0b; l0 < l0b + 512; l0 += 4){
    a0 += sv[l0 + 0]*bf2f(enc[((size_t)(b*2048 + l0 + 0))*256 + h]);
    a1 += sv[l0 + 1]*bf2f(enc[((size_t)(b*2048 + l0 + 1))*256 + h]);
    a2 += sv[l0 + 2]*bf2f(enc[((size_t)(b*2048 + l0 + 2))*256 + h]);
    a3 += sv[l0 + 3]*bf2f(enc[((size_t)(b*2048 + l0 + 3))*256 + h]);
  }
  atomicAdd(&dvec[((size_t)b*2 + x)*256 + h], ((a0 + a1) + (a2 + a3))*ri);
}

// ---------------- final FC ----------------
__global__ __launch_bounds__(64) void k_final(const float* fcw, const float* fcb, char* ws, float* outp){
  const int i = threadIdx.x;
  if (i >= 48) return;
  const int b = i/6, o = i%6;
  const float* dv = (const float*)(ws + OFS_DV);
  float acc = fcb[o];
  for (int h = 0; h < 256; ++h)
    acc += 0.5f*(dv[((size_t)b*2 + 0)*256 + h] + dv[((size_t)b*2 + 1)*256 + h])*fcw[o*256 + h];
  outp[i] = acc;
}

// ---------------- host ----------------
extern "C" void kernel_launch(void* const* d_in, const int* in_sizes, int n_in,
                              void* d_out, int out_size, void* d_ws, size_t ws_size,
                              hipStream_t stream)
{
  const int* tok    = (const int*)d_in[0];
  const int* lens   = (const int*)d_in[1];
  const float* embed= (const float*)d_in[2];
  const float* wih0 = (const float*)d_in[3];
  const float* whh0 = (const float*)d_in[4];
  const float* bih0 = (const float*)d_in[5];
  const float* bhh0 = (const float*)d_in[6];
  const float* wih1 = (const float*)d_in[7];
  const float* whh1 = (const float*)d_in[8];
  const float* bih1 = (const float*)d_in[9];
  const float* bhh1 = (const float*)d_in[10];
  const float* convw= (const float*)d_in[11];
  const float* convb= (const float*)d_in[12];
  const float* WaW  = (const float*)d_in[13];
  const float* Wab  = (const float*)d_in[14];
  const float* VTw  = (const float*)d_in[15];
  const float* VTb  = (const float*)d_in[16];
  const float* Qw   = (const float*)d_in[17];
  const float* Kw   = (const float*)d_in[18];
  const float* Vw   = (const float*)d_in[19];
  const float* fcw  = (const float*)d_in[20];
  const float* fcb  = (const float*)d_in[21];
  char* ws = (char*)d_ws;
  float* outp = (float*)d_out;

  hipLaunchKernelGGL(k_prep, dim3(1398), dim3(256), 0, stream,
      tok, lens, embed, wih0, wih1, bih0, bhh0, bih1, bhh1, convw, WaW, Qw, Kw, Vw, ws);
  hipLaunchKernelGGL((k_xg<128>), dim3(32,8,2), dim3(256), 0, stream, lens, ws);
  hipLaunchKernelGGL(k_fusedA, dim3(16 + 768 + 256), dim3(512), 0, stream,
      lens, convb, ws, whh0, (u16*)(ws + OFS_H1));
  hipLaunchKernelGGL((k_xg<256>), dim3(32,8,2), dim3(256), 0, stream, lens, ws);
  hipLaunchKernelGGL(k_fusedB, dim3(16 + 1024), dim3(512), 0, stream,
      lens, ws, whh1, (u16*)(ws + OFS_ENC));
  hipLaunchKernelGGL(k_sa, dim3(64), dim3(256), 0, stream, ws);
  hipLaunchKernelGGL(k_encres, dim3(32,8), dim3(256), 0, stream, lens, WaW, Wab, VTw, VTb, ws);
  hipLaunchKernelGGL(k_attnfin, dim3(8,2,4), dim3(256), 0, stream, ws);
  hipLaunchKernelGGL(k_final, dim3(1), dim3(64), 0, stream, fcw, fcb, ws, outp);
  (void)in_sizes; (void)n_in; (void)out_size; (void)ws_size;
}